// Round 16
// baseline (105.721 us; speedup 1.0000x reference)
//
#include <hip/hip_runtime.h>
#include <hip/hip_bf16.h>

#define D_IN  1024
#define D_H   512
#define L2E2  2.885390081777927f   // 2*log2(e)
#define ECLAMP 15.0f               // exp2-arg clamp: e in [2^-15, 2^15]

typedef _Float16 half8 __attribute__((ext_vector_type(8)));
typedef _Float16 half4v __attribute__((ext_vector_type(4)));
typedef float f32x4 __attribute__((ext_vector_type(4)));

// ---------------------------------------------------------------------------
// cvt: V (1024x1024 f32) -> Vh f16 ; [Wh;Wm] (1024x1024 f32) -> Wf f16
// (one-shot conversion; R15 proved fusing cvt into proj costs 32x redundant
// conversions + 2x L2 bytes and regresses ~8 us)
// ---------------------------------------------------------------------------
__global__ __launch_bounds__(256) void cvt_kernel(
    const float* __restrict__ V,
    const float* __restrict__ Wh, const float* __restrict__ Wm,
    _Float16* __restrict__ Vh, _Float16* __restrict__ Wf)
{
  const int idx = blockIdx.x * 256 + threadIdx.x;   // 0..262143 float4s
  {
    float4 x = ((const float4*)V)[idx];
    half4v o = { (_Float16)x.x, (_Float16)x.y, (_Float16)x.z, (_Float16)x.w };
    ((half4v*)Vh)[idx] = o;
  }
  {
    const float4* p = (idx < 131072) ? ((const float4*)Wh + idx)
                                     : ((const float4*)Wm + (idx - 131072));
    float4 x = *p;
    half4v o = { (_Float16)x.x, (_Float16)x.y, (_Float16)x.z, (_Float16)x.w };
    ((half4v*)Wf)[idx] = o;
  }
}

// ---------------------------------------------------------------------------
// proj via MFMA, k-quadrant split (R8/R13 structure): 32x32 tile, 4 waves
// each own K/4, LDS reduce, bias+exp2 epilogue. Grid 1024.
// ---------------------------------------------------------------------------
__global__ __launch_bounds__(256, 4) void proj_mfma_kernel(
    const _Float16* __restrict__ Vh, const _Float16* __restrict__ Wf,
    const float* __restrict__ bh, const float* __restrict__ bm,
    float* __restrict__ C)
{
  __shared__ float red[4][32][34];

  const int tid  = threadIdx.x;
  const int lane = tid & 63;
  const int wid  = tid >> 6;          // k-quarter 0..3
  const int bid  = blockIdx.x;
  const int swz  = (bid & 7) * 128 + (bid >> 3);
  const int i0   = (swz & 31) * 32;
  const int j0   = (swz >> 5) * 32;
  const int r16  = lane & 15;
  const int kg   = lane >> 4;         // k-group 0..3
  const int kb   = wid * 256;

  const _Float16* A0 = Vh + (size_t)(i0 + r16) * 1024 + kb + kg*8;
  const _Float16* A1 = A0 + 16 * 1024;
  const _Float16* B0 = Wf + (size_t)(j0 + r16) * 1024 + kb + kg*8;
  const _Float16* B1 = B0 + 16 * 1024;

  f32x4 acc00 = {0.f,0.f,0.f,0.f}, acc01 = acc00, acc10 = acc00, acc11 = acc00;
  #pragma unroll 4
  for (int k0 = 0; k0 < 256; k0 += 32) {
    half8 a0 = *(const half8*)(A0 + k0);
    half8 a1 = *(const half8*)(A1 + k0);
    half8 b0 = *(const half8*)(B0 + k0);
    half8 b1 = *(const half8*)(B1 + k0);
    acc00 = __builtin_amdgcn_mfma_f32_16x16x32_f16(a0, b0, acc00, 0, 0, 0);
    acc01 = __builtin_amdgcn_mfma_f32_16x16x32_f16(a0, b1, acc01, 0, 0, 0);
    acc10 = __builtin_amdgcn_mfma_f32_16x16x32_f16(a1, b0, acc10, 0, 0, 0);
    acc11 = __builtin_amdgcn_mfma_f32_16x16x32_f16(a1, b1, acc11, 0, 0, 0);
  }

  // C/D layout (m89-verified): col = lane&15, row = (lane>>4)*4 + reg
  #pragma unroll
  for (int fi = 0; fi < 2; ++fi) {
    #pragma unroll
    for (int fj = 0; fj < 2; ++fj) {
      const f32x4 acc = (fi == 0) ? (fj == 0 ? acc00 : acc01)
                                  : (fj == 0 ? acc10 : acc11);
      #pragma unroll
      for (int rr = 0; rr < 4; ++rr)
        red[wid][16*fi + 4*kg + rr][16*fj + r16] = acc[rr];
    }
  }
  __syncthreads();

  const int row = tid >> 3;
  const int c4  = (tid & 7) * 4;
  const float* biasp = (j0 < D_H) ? (bh + j0) : (bm + (j0 - D_H));
  float4 bias = *(const float4*)(biasp + c4);
  float4 o;
  #pragma unroll
  for (int q = 0; q < 4; ++q) {
    float s = red[0][row][c4+q] + red[1][row][c4+q]
            + red[2][row][c4+q] + red[3][row][c4+q];
    float x = (s + (&bias.x)[q]) * L2E2;
    x = fminf(fmaxf(x, -ECLAMP), ECLAMP);
    (&o.x)[q] = __builtin_amdgcn_exp2f(x);
  }
  *(float4*)(C + (size_t)(i0 + row) * 1024 + j0 + c4) = o;
}

// ---------------------------------------------------------------------------
// proj fallback (fp32 vector GEMM) when ws is too small for f16 staging.
// ---------------------------------------------------------------------------
__global__ __launch_bounds__(256) void proj_kernel(
    const float* __restrict__ V,
    const float* __restrict__ Wh, const float* __restrict__ bh,
    const float* __restrict__ Wm, const float* __restrict__ bm,
    float* __restrict__ C)
{
  __shared__ float As[16][68];
  __shared__ float Bs[16][68];

  const int tid = threadIdx.x;
  const int i0  = (blockIdx.x & 15) * 64, j0 = (blockIdx.x >> 4) * 64;
  const int ti  = tid >> 4, tj = tid & 15;
  const int sr  = tid >> 2;
  const int sk  = (tid & 3) << 2;

  const float* Wbase = (j0 < D_H) ? (Wh + (size_t)j0 * D_IN)
                                  : (Wm + (size_t)(j0 - D_H) * D_IN);
  const float* biasp = (j0 < D_H) ? (bh + j0) : (bm + (j0 - D_H));

  const float* arow = V     + (size_t)(i0 + sr) * D_IN + sk;
  const float* brow = Wbase + (size_t)sr        * D_IN + sk;

  float acc[4][4] = {};
  for (int k0 = 0; k0 < D_IN; k0 += 16) {
    float4 av = *(const float4*)(arow + k0);
    float4 bv = *(const float4*)(brow + k0);
    As[sk+0][sr] = av.x; As[sk+1][sr] = av.y; As[sk+2][sr] = av.z; As[sk+3][sr] = av.w;
    Bs[sk+0][sr] = bv.x; Bs[sk+1][sr] = bv.y; Bs[sk+2][sr] = bv.z; Bs[sk+3][sr] = bv.w;
    __syncthreads();
    #pragma unroll
    for (int kk = 0; kk < 16; ++kk) {
      float4 a = *(const float4*)&As[kk][4*ti];
      float4 b = *(const float4*)&Bs[kk][4*tj];
      #pragma unroll
      for (int x = 0; x < 4; ++x)
        #pragma unroll
        for (int y = 0; y < 4; ++y)
          acc[x][y] = fmaf((&a.x)[x], (&b.x)[y], acc[x][y]);
    }
    __syncthreads();
  }

  const int jl = 4 * tj;
  #pragma unroll
  for (int aa = 0; aa < 4; ++aa) {
    const int i = i0 + 4*ti + aa;
    float4 o;
    #pragma unroll
    for (int bb = 0; bb < 4; ++bb) {
      float x = (acc[aa][bb] + biasp[jl+bb]) * L2E2;
      x = fminf(fmaxf(x, -ECLAMP), ECLAMP);
      (&o.x)[bb] = __builtin_amdgcn_exp2f(x);
    }
    *(float4*)(C + (size_t)i * 1024 + j0 + jl) = o;
  }
}

// ---------------------------------------------------------------------------
// score_gd: GLOBAL-DIRECT score. 64x64 tile, 4x4/thread, K-quarter per
// block (grid 1024). NO LDS staging: eh loads are 16-lane broadcasts
// (4 rows/wave), em loads stream 64-row column slices whose 64B lines each
// serve 4 k-groups (L1-resident window ~8KB/4 groups). Zero barriers in the
// main loop; wred needs one. VALU:VMEM ~ 28:1 hides L1/L2 latency.
// Partials stored as f16 planes; kh=0 plane carries base. XCD swizzle.
// ---------------------------------------------------------------------------
__global__ __launch_bounds__(256, 2) void score_gd_kernel(
    const float* __restrict__ C,
    const float* __restrict__ w2,
    const float* __restrict__ b2,
    _Float16* __restrict__ P0, _Float16* __restrict__ P1,
    _Float16* __restrict__ P2, _Float16* __restrict__ P3)
{
  __shared__ float wred[4];

  const int tid  = threadIdx.x;
  const int b    = blockIdx.x;
  const int v    = (b & 7) * 128 + (b >> 3);   // XCD-grouped virtual id
  const int tile = v >> 2;
  const int kh   = v & 3;
  const int i0   = (tile & 15) * 64;
  const int j0   = (tile >> 4) * 64;
  const int kb   = kh * 128;
  const int ti   = tid >> 4, tj = tid & 15;    // outputs: i0+ti+16a, j0+tj+16c

  if (kh == 0) {            // block-uniform branch
    float sw = 0.f;
    for (int t = tid; t < D_H; t += 256) sw += w2[t];
    #pragma unroll
    for (int off = 32; off > 0; off >>= 1) sw += __shfl_down(sw, off, 64);
    if ((tid & 63) == 0) wred[tid >> 6] = sw;
  }
  __syncthreads();          // wred visibility (only barrier in kernel)

  const float* ehb = C + (size_t)(i0 + ti) * 1024 + kb;         // +a*16*1024
  const float* emb = C + (size_t)(j0 + tj) * 1024 + D_H + kb;   // +c*16*1024

  float acc[4][4] = {};

  #pragma unroll 4
  for (int g = 0; g < 32; ++g) {
    const int kk = 4 * g;
    float4 eh[4], em[4];
    #pragma unroll
    for (int a = 0; a < 4; ++a)
      eh[a] = *(const float4*)(ehb + (size_t)a * 16384 + kk);
    #pragma unroll
    for (int c = 0; c < 4; ++c)
      em[c] = *(const float4*)(emb + (size_t)c * 16384 + kk);

    const float wA = w2[kb + kk + 0];
    const float wB = w2[kb + kk + 1];
    const float wC = w2[kb + kk + 2];
    const float wD = w2[kb + kk + 3];
    #pragma unroll
    for (int a = 0; a < 4; ++a) {
      #pragma unroll
      for (int c = 0; c < 4; ++c) {
        float uA = fmaf(eh[a].x, em[c].x, 1.f);
        float uB = fmaf(eh[a].y, em[c].y, 1.f);
        float uC = fmaf(eh[a].z, em[c].z, 1.f);
        float uD = fmaf(eh[a].w, em[c].w, 1.f);
        float dAB = uA * uB, dCD = uC * uD;
        float nAB = fmaf(wB, uA, wA * uB);
        float nCD = fmaf(wD, uC, wC * uD);
        float den = dAB * dCD;
        float num = fmaf(nCD, dAB, nAB * dCD);
        acc[a][c] = fmaf(num, __builtin_amdgcn_rcpf(den), acc[a][c]);
      }
    }
  }

  float base = 0.f;
  if (kh == 0) base = b2[0] + wred[0] + wred[1] + wred[2] + wred[3];
  _Float16* Pz = (kh == 0) ? P0 : (kh == 1) ? P1 : (kh == 2) ? P2 : P3;
  #pragma unroll
  for (int a = 0; a < 4; ++a) {
    const int i = i0 + ti + 16*a;
    #pragma unroll
    for (int c = 0; c < 4; ++c) {
      const int j = j0 + tj + 16*c;
      Pz[(size_t)i * 1024 + j] = (_Float16)fmaf(-2.f, acc[a][c], base);
    }
  }
}

// combine: out = P0 + P1 + P2 + P3 (f16 planes -> f32)
__global__ __launch_bounds__(256) void combine_kernel(
    const _Float16* __restrict__ P0, const _Float16* __restrict__ P1,
    const _Float16* __restrict__ P2, const _Float16* __restrict__ P3,
    float* __restrict__ out)
{
  const int idx = blockIdx.x * 256 + threadIdx.x;   // 0..262143 quads
  half4v a = ((const half4v*)P0)[idx];
  half4v b = ((const half4v*)P1)[idx];
  half4v c = ((const half4v*)P2)[idx];
  half4v d = ((const half4v*)P3)[idx];
  float4 o;
  #pragma unroll
  for (int q = 0; q < 4; ++q)
    (&o.x)[q] = (float)a[q] + (float)b[q] + ((float)c[q] + (float)d[q]);
  ((float4*)out)[idx] = o;
}

// ---------------------------------------------------------------------------
// score fallback (R9, proven 60.2 us): 64x32 tile, 4x2/thread, grid 512.
// Writes f32 out directly; needs only the 4 MB C plane.
// ---------------------------------------------------------------------------
__global__ __launch_bounds__(256, 2) void score_kernel_r9(
    const float* __restrict__ C,
    const float* __restrict__ w2,
    const float* __restrict__ b2,
    float* __restrict__ out)
{
  __shared__ float hs[2][64][36];
  __shared__ float ms[2][32][36];
  __shared__ float wred[4];

  const int tid = threadIdx.x;
  const int bi  = blockIdx.x & 15;
  const int bj  = blockIdx.x >> 4;
  const int i0  = bi * 64, j0 = bj * 32;
  const int ti  = tid >> 4, tj = tid & 15;

  const int sr  = tid >> 3;
  const int sk  = (tid & 7) << 2;

  float sw = 0.f;
  for (int t = tid; t < D_H; t += 256) sw += w2[t];
  #pragma unroll
  for (int off = 32; off > 0; off >>= 1) sw += __shfl_down(sw, off, 64);
  if ((tid & 63) == 0) wred[tid >> 6] = sw;

  const float* hrow0 = C + (size_t)(i0 + sr)      * 1024 + sk;
  const float* hrow1 = C + (size_t)(i0 + sr + 32) * 1024 + sk;
  const float* mrow  = C + (size_t)(j0 + sr) * 1024 + D_H + sk;

  float4 hv0 = *(const float4*)(hrow0);
  float4 hv1 = *(const float4*)(hrow1);
  float4 mv  = *(const float4*)(mrow);

  float acc[4][2] = {};
  int p = 0;

  for (int k0 = 0; k0 < D_H; k0 += 32) {
    *(float4*)&hs[p][sr][sk]      = hv0;
    *(float4*)&hs[p][sr + 32][sk] = hv1;
    *(float4*)&ms[p][sr][sk]      = mv;
    __syncthreads();

    if (k0 + 32 < D_H) {
      hv0 = *(const float4*)(hrow0 + k0 + 32);
      hv1 = *(const float4*)(hrow1 + k0 + 32);
      mv  = *(const float4*)(mrow  + k0 + 32);
    }

    #pragma unroll
    for (int g = 0; g < 8; ++g) {
      const int kk = 4 * g;
      float4 eh[4];
      float4 em[2];
      #pragma unroll
      for (int a = 0; a < 4; ++a)
        eh[a] = *(const float4*)&hs[p][ti + 16*a][kk];
      #pragma unroll
      for (int c = 0; c < 2; ++c)
        em[c] = *(const float4*)&ms[p][tj + 16*c][kk];

      const float wA = w2[k0 + kk + 0];
      const float wB = w2[k0 + kk + 1];
      const float wC = w2[k0 + kk + 2];
      const float wD = w2[k0 + kk + 3];
      #pragma unroll
      for (int a = 0; a < 4; ++a) {
        #pragma unroll
        for (int c = 0; c < 2; ++c) {
          float uA = fmaf(eh[a].x, em[c].x, 1.f);
          float uB = fmaf(eh[a].y, em[c].y, 1.f);
          float uC = fmaf(eh[a].z, em[c].z, 1.f);
          float uD = fmaf(eh[a].w, em[c].w, 1.f);
          float dAB = uA * uB, dCD = uC * uD;
          float nAB = fmaf(wB, uA, wA * uB);
          float nCD = fmaf(wD, uC, wC * uD);
          float den = dAB * dCD;
          float num = fmaf(nCD, dAB, nAB * dCD);
          acc[a][c] = fmaf(num, __builtin_amdgcn_rcpf(den), acc[a][c]);
        }
      }
    }
    p ^= 1;
  }

  const float base = b2[0] + wred[0] + wred[1] + wred[2] + wred[3];
  #pragma unroll
  for (int a = 0; a < 4; ++a) {
    const int i = i0 + ti + 16*a;
    #pragma unroll
    for (int c = 0; c < 2; ++c) {
      const int j = j0 + tj + 16*c;
      out[(size_t)i * 1024 + j] = fmaf(-2.f, acc[a][c], base);
    }
  }
}

extern "C" void kernel_launch(void* const* d_in, const int* in_sizes, int n_in,
                              void* d_out, int out_size, void* d_ws, size_t ws_size,
                              hipStream_t stream) {
  const float* V  = (const float*)d_in[0];
  const float* Wh = (const float*)d_in[1];
  const float* bh = (const float*)d_in[2];
  const float* Wm = (const float*)d_in[3];
  const float* bm = (const float*)d_in[4];
  const float* w2 = (const float*)d_in[5];
  const float* b2 = (const float*)d_in[6];
  float* outp = (float*)d_out;

  char* ws = (char*)d_ws;
  float* C = (float*)ws;                                 // 4 MB: Eh|Em

  if (ws_size >= (size_t)(16u << 20)) {
    _Float16* Vh = (_Float16*)(ws + (4u << 20));         // 2 MB
    _Float16* Wf = (_Float16*)(ws + (6u << 20));         // 2 MB
    _Float16* P0 = (_Float16*)(ws + (8u << 20));         // 2 MB each
    _Float16* P1 = (_Float16*)(ws + (10u << 20));
    _Float16* P2 = (_Float16*)(ws + (12u << 20));
    _Float16* P3 = (_Float16*)(ws + (14u << 20));
    cvt_kernel<<<dim3(1024), dim3(256), 0, stream>>>(V, Wh, Wm, Vh, Wf);
    proj_mfma_kernel<<<dim3(1024), dim3(256), 0, stream>>>(Vh, Wf, bh, bm, C);
    score_gd_kernel<<<dim3(1024), dim3(256), 0, stream>>>(C, w2, b2, P0, P1, P2, P3);
    combine_kernel<<<dim3(1024), dim3(256), 0, stream>>>(P0, P1, P2, P3, outp);
  } else if (ws_size >= (size_t)(8u << 20)) {
    _Float16* Vh = (_Float16*)(ws + (4u << 20));         // 2 MB
    _Float16* Wf = (_Float16*)(ws + (6u << 20));         // 2 MB
    cvt_kernel<<<dim3(1024), dim3(256), 0, stream>>>(V, Wh, Wm, Vh, Wf);
    proj_mfma_kernel<<<dim3(1024), dim3(256), 0, stream>>>(Vh, Wf, bh, bm, C);
    score_kernel_r9<<<dim3(512), dim3(256), 0, stream>>>(C, w2, b2, outp);
  } else {
    proj_kernel<<<dim3(256), dim3(256), 0, stream>>>(V, Wh, bh, Wm, bm, C);
    score_kernel_r9<<<dim3(512), dim3(256), 0, stream>>>(C, w2, b2, outp);
  }
}

// Round 17
// 98.562 us; speedup vs baseline: 1.0726x; 1.0726x over previous
//
#include <hip/hip_runtime.h>
#include <hip/hip_bf16.h>

#define D_IN  1024
#define D_H   512
#define L2E2  2.885390081777927f   // 2*log2(e)
#define ECLAMP 15.0f               // exp2-arg clamp: e in [2^-15, 2^15]

typedef _Float16 half8 __attribute__((ext_vector_type(8)));
typedef _Float16 half4v __attribute__((ext_vector_type(4)));
typedef float f32x4 __attribute__((ext_vector_type(4)));

// ---------------------------------------------------------------------------
// cvt: V (1024x1024 f32) -> Vh f16 ; [Wh;Wm] (1024x1024 f32) -> Wf f16
// ---------------------------------------------------------------------------
__global__ __launch_bounds__(256) void cvt_kernel(
    const float* __restrict__ V,
    const float* __restrict__ Wh, const float* __restrict__ Wm,
    _Float16* __restrict__ Vh, _Float16* __restrict__ Wf)
{
  const int idx = blockIdx.x * 256 + threadIdx.x;   // 0..262143 float4s
  {
    float4 x = ((const float4*)V)[idx];
    half4v o = { (_Float16)x.x, (_Float16)x.y, (_Float16)x.z, (_Float16)x.w };
    ((half4v*)Vh)[idx] = o;
  }
  {
    const float4* p = (idx < 131072) ? ((const float4*)Wh + idx)
                                     : ((const float4*)Wm + (idx - 131072));
    float4 x = *p;
    half4v o = { (_Float16)x.x, (_Float16)x.y, (_Float16)x.z, (_Float16)x.w };
    ((half4v*)Wf)[idx] = o;
  }
}

// ---------------------------------------------------------------------------
// proj via MFMA, k-quadrant split (R8/R13 structure): 32x32 tile, 4 waves
// each own K/4, LDS reduce, bias+exp2 epilogue. Grid 1024.
// ---------------------------------------------------------------------------
__global__ __launch_bounds__(256, 4) void proj_mfma_kernel(
    const _Float16* __restrict__ Vh, const _Float16* __restrict__ Wf,
    const float* __restrict__ bh, const float* __restrict__ bm,
    float* __restrict__ C)
{
  __shared__ float red[4][32][34];

  const int tid  = threadIdx.x;
  const int lane = tid & 63;
  const int wid  = tid >> 6;          // k-quarter 0..3
  const int bid  = blockIdx.x;
  const int swz  = (bid & 7) * 128 + (bid >> 3);
  const int i0   = (swz & 31) * 32;
  const int j0   = (swz >> 5) * 32;
  const int r16  = lane & 15;
  const int kg   = lane >> 4;         // k-group 0..3
  const int kb   = wid * 256;

  const _Float16* A0 = Vh + (size_t)(i0 + r16) * 1024 + kb + kg*8;
  const _Float16* A1 = A0 + 16 * 1024;
  const _Float16* B0 = Wf + (size_t)(j0 + r16) * 1024 + kb + kg*8;
  const _Float16* B1 = B0 + 16 * 1024;

  f32x4 acc00 = {0.f,0.f,0.f,0.f}, acc01 = acc00, acc10 = acc00, acc11 = acc00;
  #pragma unroll 4
  for (int k0 = 0; k0 < 256; k0 += 32) {
    half8 a0 = *(const half8*)(A0 + k0);
    half8 a1 = *(const half8*)(A1 + k0);
    half8 b0 = *(const half8*)(B0 + k0);
    half8 b1 = *(const half8*)(B1 + k0);
    acc00 = __builtin_amdgcn_mfma_f32_16x16x32_f16(a0, b0, acc00, 0, 0, 0);
    acc01 = __builtin_amdgcn_mfma_f32_16x16x32_f16(a0, b1, acc01, 0, 0, 0);
    acc10 = __builtin_amdgcn_mfma_f32_16x16x32_f16(a1, b0, acc10, 0, 0, 0);
    acc11 = __builtin_amdgcn_mfma_f32_16x16x32_f16(a1, b1, acc11, 0, 0, 0);
  }

  // C/D layout (m89-verified): col = lane&15, row = (lane>>4)*4 + reg
  #pragma unroll
  for (int fi = 0; fi < 2; ++fi) {
    #pragma unroll
    for (int fj = 0; fj < 2; ++fj) {
      const f32x4 acc = (fi == 0) ? (fj == 0 ? acc00 : acc01)
                                  : (fj == 0 ? acc10 : acc11);
      #pragma unroll
      for (int rr = 0; rr < 4; ++rr)
        red[wid][16*fi + 4*kg + rr][16*fj + r16] = acc[rr];
    }
  }
  __syncthreads();

  const int row = tid >> 3;
  const int c4  = (tid & 7) * 4;
  const float* biasp = (j0 < D_H) ? (bh + j0) : (bm + (j0 - D_H));
  float4 bias = *(const float4*)(biasp + c4);
  float4 o;
  #pragma unroll
  for (int q = 0; q < 4; ++q) {
    float s = red[0][row][c4+q] + red[1][row][c4+q]
            + red[2][row][c4+q] + red[3][row][c4+q];
    float x = (s + (&bias.x)[q]) * L2E2;
    x = fminf(fmaxf(x, -ECLAMP), ECLAMP);
    (&o.x)[q] = __builtin_amdgcn_exp2f(x);
  }
  *(float4*)(C + (size_t)(i0 + row) * 1024 + j0 + c4) = o;
}

// ---------------------------------------------------------------------------
// proj fallback (fp32 vector GEMM) when ws is too small for f16 staging.
// ---------------------------------------------------------------------------
__global__ __launch_bounds__(256) void proj_kernel(
    const float* __restrict__ V,
    const float* __restrict__ Wh, const float* __restrict__ bh,
    const float* __restrict__ Wm, const float* __restrict__ bm,
    float* __restrict__ C)
{
  __shared__ float As[16][68];
  __shared__ float Bs[16][68];

  const int tid = threadIdx.x;
  const int i0  = (blockIdx.x & 15) * 64, j0 = (blockIdx.x >> 4) * 64;
  const int ti  = tid >> 4, tj = tid & 15;
  const int sr  = tid >> 2;
  const int sk  = (tid & 3) << 2;

  const float* Wbase = (j0 < D_H) ? (Wh + (size_t)j0 * D_IN)
                                  : (Wm + (size_t)(j0 - D_H) * D_IN);
  const float* biasp = (j0 < D_H) ? (bh + j0) : (bm + (j0 - D_H));

  const float* arow = V     + (size_t)(i0 + sr) * D_IN + sk;
  const float* brow = Wbase + (size_t)sr        * D_IN + sk;

  float acc[4][4] = {};
  for (int k0 = 0; k0 < D_IN; k0 += 16) {
    float4 av = *(const float4*)(arow + k0);
    float4 bv = *(const float4*)(brow + k0);
    As[sk+0][sr] = av.x; As[sk+1][sr] = av.y; As[sk+2][sr] = av.z; As[sk+3][sr] = av.w;
    Bs[sk+0][sr] = bv.x; Bs[sk+1][sr] = bv.y; Bs[sk+2][sr] = bv.z; Bs[sk+3][sr] = bv.w;
    __syncthreads();
    #pragma unroll
    for (int kk = 0; kk < 16; ++kk) {
      float4 a = *(const float4*)&As[kk][4*ti];
      float4 b = *(const float4*)&Bs[kk][4*tj];
      #pragma unroll
      for (int x = 0; x < 4; ++x)
        #pragma unroll
        for (int y = 0; y < 4; ++y)
          acc[x][y] = fmaf((&a.x)[x], (&b.x)[y], acc[x][y]);
    }
    __syncthreads();
  }

  const int jl = 4 * tj;
  #pragma unroll
  for (int aa = 0; aa < 4; ++aa) {
    const int i = i0 + 4*ti + aa;
    float4 o;
    #pragma unroll
    for (int bb = 0; bb < 4; ++bb) {
      float x = (acc[aa][bb] + biasp[jl+bb]) * L2E2;
      x = fminf(fmaxf(x, -ECLAMP), ECLAMP);
      (&o.x)[bb] = __builtin_amdgcn_exp2f(x);
    }
    *(float4*)(C + (size_t)i * 1024 + j0 + jl) = o;
  }
}

// ---------------------------------------------------------------------------
// score_q (R13 structure + w2-in-LDS): 64x64 tile, 4x4/thread, K-quarter
// per block (grid 1024). w2 staged in LDS once -> inner loop is DS-ops only
// (no SMEM/LDS lgkmcnt mixing -> counted waits instead of lgkmcnt(0) drains).
// Partials stored as f16 planes; kh=0 plane carries base. XCD swizzle.
// ---------------------------------------------------------------------------
__global__ __launch_bounds__(256, 2) void score_q_kernel(
    const float* __restrict__ C,
    const float* __restrict__ w2,
    const float* __restrict__ b2,
    _Float16* __restrict__ P0, _Float16* __restrict__ P1,
    _Float16* __restrict__ P2, _Float16* __restrict__ P3)
{
  __shared__ float hs[2][64][36];
  __shared__ float ms[2][64][36];
  __shared__ float wls[128];        // this quarter's w2 slice
  __shared__ float wred[4];

  const int tid  = threadIdx.x;
  const int b    = blockIdx.x;
  const int v    = (b & 7) * 128 + (b >> 3);   // XCD-grouped virtual id
  const int tile = v >> 2;
  const int kh   = v & 3;
  const int i0   = (tile & 15) * 64;
  const int j0   = (tile >> 4) * 64;
  const int kb   = kh * 128;
  const int ti   = tid >> 4, tj = tid & 15;    // outputs: i0+ti+16a, j0+tj+16c

  const int sr   = tid >> 3;                   // staging row 0..31
  const int sk   = (tid & 7) << 2;             // staging k 0..28

  // stage this quarter's w2 into LDS (and block-reduce sum(w2) on kh==0)
  if (tid < 128) wls[tid] = w2[kb + tid];
  if (kh == 0) {            // block-uniform branch
    float sw = 0.f;
    for (int t = tid; t < D_H; t += 256) sw += w2[t];
    #pragma unroll
    for (int off = 32; off > 0; off >>= 1) sw += __shfl_down(sw, off, 64);
    if ((tid & 63) == 0) wred[tid >> 6] = sw;
  }

  const float* hrow0 = C + (size_t)(i0 + sr)      * 1024 + kb + sk;
  const float* hrow1 = C + (size_t)(i0 + sr + 32) * 1024 + kb + sk;
  const float* mrow0 = C + (size_t)(j0 + sr)      * 1024 + D_H + kb + sk;
  const float* mrow1 = C + (size_t)(j0 + sr + 32) * 1024 + D_H + kb + sk;

  float4 hv0 = *(const float4*)(hrow0);
  float4 hv1 = *(const float4*)(hrow1);
  float4 mv0 = *(const float4*)(mrow0);
  float4 mv1 = *(const float4*)(mrow1);

  float acc[4][4] = {};
  int p = 0;

  for (int k0 = 0; k0 < 128; k0 += 32) {
    *(float4*)&hs[p][sr][sk]      = hv0;
    *(float4*)&hs[p][sr + 32][sk] = hv1;
    *(float4*)&ms[p][sr][sk]      = mv0;
    *(float4*)&ms[p][sr + 32][sk] = mv1;
    __syncthreads();          // also covers wls/wred on first iteration

    if (k0 + 32 < 128) {
      hv0 = *(const float4*)(hrow0 + k0 + 32);
      hv1 = *(const float4*)(hrow1 + k0 + 32);
      mv0 = *(const float4*)(mrow0 + k0 + 32);
      mv1 = *(const float4*)(mrow1 + k0 + 32);
    }

    #pragma unroll
    for (int g = 0; g < 8; ++g) {
      const int kk = 4 * g;
      float4 eh[4], em[4];
      float4 wv = *(const float4*)&wls[k0 + kk];   // ds_read, broadcast
      #pragma unroll
      for (int a = 0; a < 4; ++a)
        eh[a] = *(const float4*)&hs[p][ti + 16*a][kk];
      #pragma unroll
      for (int c = 0; c < 4; ++c)
        em[c] = *(const float4*)&ms[p][tj + 16*c][kk];

      #pragma unroll
      for (int a = 0; a < 4; ++a) {
        #pragma unroll
        for (int c = 0; c < 4; ++c) {
          float uA = fmaf(eh[a].x, em[c].x, 1.f);
          float uB = fmaf(eh[a].y, em[c].y, 1.f);
          float uC = fmaf(eh[a].z, em[c].z, 1.f);
          float uD = fmaf(eh[a].w, em[c].w, 1.f);
          float dAB = uA * uB, dCD = uC * uD;
          float nAB = fmaf(wv.y, uA, wv.x * uB);
          float nCD = fmaf(wv.w, uC, wv.z * uD);
          float den = dAB * dCD;
          float num = fmaf(nCD, dAB, nAB * dCD);
          acc[a][c] = fmaf(num, __builtin_amdgcn_rcpf(den), acc[a][c]);
        }
      }
    }
    p ^= 1;
  }

  float base = 0.f;
  if (kh == 0) base = b2[0] + wred[0] + wred[1] + wred[2] + wred[3];
  _Float16* Pz = (kh == 0) ? P0 : (kh == 1) ? P1 : (kh == 2) ? P2 : P3;
  #pragma unroll
  for (int a = 0; a < 4; ++a) {
    const int i = i0 + ti + 16*a;
    #pragma unroll
    for (int c = 0; c < 4; ++c) {
      const int j = j0 + tj + 16*c;
      Pz[(size_t)i * 1024 + j] = (_Float16)fmaf(-2.f, acc[a][c], base);
    }
  }
}

// combine: out = P0 + P1 + P2 + P3 (f16 planes -> f32)
__global__ __launch_bounds__(256) void combine_kernel(
    const _Float16* __restrict__ P0, const _Float16* __restrict__ P1,
    const _Float16* __restrict__ P2, const _Float16* __restrict__ P3,
    float* __restrict__ out)
{
  const int idx = blockIdx.x * 256 + threadIdx.x;   // 0..262143 quads
  half4v a = ((const half4v*)P0)[idx];
  half4v b = ((const half4v*)P1)[idx];
  half4v c = ((const half4v*)P2)[idx];
  half4v d = ((const half4v*)P3)[idx];
  float4 o;
  #pragma unroll
  for (int q = 0; q < 4; ++q)
    (&o.x)[q] = (float)a[q] + (float)b[q] + ((float)c[q] + (float)d[q]);
  ((float4*)out)[idx] = o;
}

// ---------------------------------------------------------------------------
// score fallback (R9 structure + w2-in-LDS): 64x32 tile, 4x2/thread, grid 512.
// ---------------------------------------------------------------------------
__global__ __launch_bounds__(256, 2) void score_kernel_r9(
    const float* __restrict__ C,
    const float* __restrict__ w2,
    const float* __restrict__ b2,
    float* __restrict__ out)
{
  __shared__ float hs[2][64][36];
  __shared__ float ms[2][32][36];
  __shared__ float wls[D_H];
  __shared__ float wred[4];

  const int tid = threadIdx.x;
  const int bi  = blockIdx.x & 15;
  const int bj  = blockIdx.x >> 4;
  const int i0  = bi * 64, j0 = bj * 32;
  const int ti  = tid >> 4, tj = tid & 15;

  const int sr  = tid >> 3;
  const int sk  = (tid & 7) << 2;

  float sw = 0.f;
  for (int t = tid; t < D_H; t += 256) { float w = w2[t]; wls[t] = w; sw += w; }
  #pragma unroll
  for (int off = 32; off > 0; off >>= 1) sw += __shfl_down(sw, off, 64);
  if ((tid & 63) == 0) wred[tid >> 6] = sw;

  const float* hrow0 = C + (size_t)(i0 + sr)      * 1024 + sk;
  const float* hrow1 = C + (size_t)(i0 + sr + 32) * 1024 + sk;
  const float* mrow  = C + (size_t)(j0 + sr) * 1024 + D_H + sk;

  float4 hv0 = *(const float4*)(hrow0);
  float4 hv1 = *(const float4*)(hrow1);
  float4 mv  = *(const float4*)(mrow);

  float acc[4][2] = {};
  int p = 0;

  for (int k0 = 0; k0 < D_H; k0 += 32) {
    *(float4*)&hs[p][sr][sk]      = hv0;
    *(float4*)&hs[p][sr + 32][sk] = hv1;
    *(float4*)&ms[p][sr][sk]      = mv;
    __syncthreads();

    if (k0 + 32 < D_H) {
      hv0 = *(const float4*)(hrow0 + k0 + 32);
      hv1 = *(const float4*)(hrow1 + k0 + 32);
      mv  = *(const float4*)(mrow  + k0 + 32);
    }

    #pragma unroll
    for (int g = 0; g < 8; ++g) {
      const int kk = 4 * g;
      float4 eh[4];
      float4 em[2];
      float4 wv = *(const float4*)&wls[k0 + kk];
      #pragma unroll
      for (int a = 0; a < 4; ++a)
        eh[a] = *(const float4*)&hs[p][ti + 16*a][kk];
      #pragma unroll
      for (int c = 0; c < 2; ++c)
        em[c] = *(const float4*)&ms[p][tj + 16*c][kk];

      #pragma unroll
      for (int a = 0; a < 4; ++a) {
        #pragma unroll
        for (int c = 0; c < 2; ++c) {
          float uA = fmaf(eh[a].x, em[c].x, 1.f);
          float uB = fmaf(eh[a].y, em[c].y, 1.f);
          float uC = fmaf(eh[a].z, em[c].z, 1.f);
          float uD = fmaf(eh[a].w, em[c].w, 1.f);
          float dAB = uA * uB, dCD = uC * uD;
          float nAB = fmaf(wv.y, uA, wv.x * uB);
          float nCD = fmaf(wv.w, uC, wv.z * uD);
          float den = dAB * dCD;
          float num = fmaf(nCD, dAB, nAB * dCD);
          acc[a][c] = fmaf(num, __builtin_amdgcn_rcpf(den), acc[a][c]);
        }
      }
    }
    p ^= 1;
  }

  const float base = b2[0] + wred[0] + wred[1] + wred[2] + wred[3];
  #pragma unroll
  for (int a = 0; a < 4; ++a) {
    const int i = i0 + ti + 16*a;
    #pragma unroll
    for (int c = 0; c < 2; ++c) {
      const int j = j0 + tj + 16*c;
      out[(size_t)i * 1024 + j] = fmaf(-2.f, acc[a][c], base);
    }
  }
}

extern "C" void kernel_launch(void* const* d_in, const int* in_sizes, int n_in,
                              void* d_out, int out_size, void* d_ws, size_t ws_size,
                              hipStream_t stream) {
  const float* V  = (const float*)d_in[0];
  const float* Wh = (const float*)d_in[1];
  const float* bh = (const float*)d_in[2];
  const float* Wm = (const float*)d_in[3];
  const float* bm = (const float*)d_in[4];
  const float* w2 = (const float*)d_in[5];
  const float* b2 = (const float*)d_in[6];
  float* outp = (float*)d_out;

  char* ws = (char*)d_ws;
  float* C = (float*)ws;                                 // 4 MB: Eh|Em

  if (ws_size >= (size_t)(16u << 20)) {
    _Float16* Vh = (_Float16*)(ws + (4u << 20));         // 2 MB
    _Float16* Wf = (_Float16*)(ws + (6u << 20));         // 2 MB
    _Float16* P0 = (_Float16*)(ws + (8u << 20));         // 2 MB each
    _Float16* P1 = (_Float16*)(ws + (10u << 20));
    _Float16* P2 = (_Float16*)(ws + (12u << 20));
    _Float16* P3 = (_Float16*)(ws + (14u << 20));
    cvt_kernel<<<dim3(1024), dim3(256), 0, stream>>>(V, Wh, Wm, Vh, Wf);
    proj_mfma_kernel<<<dim3(1024), dim3(256), 0, stream>>>(Vh, Wf, bh, bm, C);
    score_q_kernel<<<dim3(1024), dim3(256), 0, stream>>>(C, w2, b2, P0, P1, P2, P3);
    combine_kernel<<<dim3(1024), dim3(256), 0, stream>>>(P0, P1, P2, P3, outp);
  } else if (ws_size >= (size_t)(8u << 20)) {
    _Float16* Vh = (_Float16*)(ws + (4u << 20));         // 2 MB
    _Float16* Wf = (_Float16*)(ws + (6u << 20));         // 2 MB
    cvt_kernel<<<dim3(1024), dim3(256), 0, stream>>>(V, Wh, Wm, Vh, Wf);
    proj_mfma_kernel<<<dim3(1024), dim3(256), 0, stream>>>(Vh, Wf, bh, bm, C);
    score_kernel_r9<<<dim3(512), dim3(256), 0, stream>>>(C, w2, b2, outp);
  } else {
    proj_kernel<<<dim3(256), dim3(256), 0, stream>>>(V, Wh, bh, Wm, bm, C);
    score_kernel_r9<<<dim3(512), dim3(256), 0, stream>>>(C, w2, b2, outp);
  }
}

// Round 18
// 77.431 us; speedup vs baseline: 1.3654x; 1.2729x over previous
//
#include <hip/hip_runtime.h>
#include <hip/hip_bf16.h>

#define D_IN  1024
#define D_H   512
#define L2E2  2.885390081777927f   // 2*log2(e)
#define ECLAMP 15.0f               // exp2-arg clamp: e in [2^-15, 2^15]

typedef _Float16 half8 __attribute__((ext_vector_type(8)));
typedef _Float16 half4v __attribute__((ext_vector_type(4)));
typedef float f32x4 __attribute__((ext_vector_type(4)));

// ---------------------------------------------------------------------------
// cvt: V (1024x1024 f32) -> Vh f16 ; [Wh;Wm] (1024x1024 f32) -> Wf f16
// ---------------------------------------------------------------------------
__global__ __launch_bounds__(256) void cvt_kernel(
    const float* __restrict__ V,
    const float* __restrict__ Wh, const float* __restrict__ Wm,
    _Float16* __restrict__ Vh, _Float16* __restrict__ Wf)
{
  const int idx = blockIdx.x * 256 + threadIdx.x;   // 0..262143 float4s
  {
    float4 x = ((const float4*)V)[idx];
    half4v o = { (_Float16)x.x, (_Float16)x.y, (_Float16)x.z, (_Float16)x.w };
    ((half4v*)Vh)[idx] = o;
  }
  {
    const float4* p = (idx < 131072) ? ((const float4*)Wh + idx)
                                     : ((const float4*)Wm + (idx - 131072));
    float4 x = *p;
    half4v o = { (_Float16)x.x, (_Float16)x.y, (_Float16)x.z, (_Float16)x.w };
    ((half4v*)Wf)[idx] = o;
  }
}

// ---------------------------------------------------------------------------
// proj via MFMA, k-quadrant split (R8/R13 structure): 32x32 tile, 4 waves
// each own K/4, LDS reduce, bias+exp2 epilogue. Grid 1024.
// ---------------------------------------------------------------------------
__global__ __launch_bounds__(256, 4) void proj_mfma_kernel(
    const _Float16* __restrict__ Vh, const _Float16* __restrict__ Wf,
    const float* __restrict__ bh, const float* __restrict__ bm,
    float* __restrict__ C)
{
  __shared__ float red[4][32][34];

  const int tid  = threadIdx.x;
  const int lane = tid & 63;
  const int wid  = tid >> 6;          // k-quarter 0..3
  const int bid  = blockIdx.x;
  const int swz  = (bid & 7) * 128 + (bid >> 3);
  const int i0   = (swz & 31) * 32;
  const int j0   = (swz >> 5) * 32;
  const int r16  = lane & 15;
  const int kg   = lane >> 4;         // k-group 0..3
  const int kb   = wid * 256;

  const _Float16* A0 = Vh + (size_t)(i0 + r16) * 1024 + kb + kg*8;
  const _Float16* A1 = A0 + 16 * 1024;
  const _Float16* B0 = Wf + (size_t)(j0 + r16) * 1024 + kb + kg*8;
  const _Float16* B1 = B0 + 16 * 1024;

  f32x4 acc00 = {0.f,0.f,0.f,0.f}, acc01 = acc00, acc10 = acc00, acc11 = acc00;
  #pragma unroll 4
  for (int k0 = 0; k0 < 256; k0 += 32) {
    half8 a0 = *(const half8*)(A0 + k0);
    half8 a1 = *(const half8*)(A1 + k0);
    half8 b0 = *(const half8*)(B0 + k0);
    half8 b1 = *(const half8*)(B1 + k0);
    acc00 = __builtin_amdgcn_mfma_f32_16x16x32_f16(a0, b0, acc00, 0, 0, 0);
    acc01 = __builtin_amdgcn_mfma_f32_16x16x32_f16(a0, b1, acc01, 0, 0, 0);
    acc10 = __builtin_amdgcn_mfma_f32_16x16x32_f16(a1, b0, acc10, 0, 0, 0);
    acc11 = __builtin_amdgcn_mfma_f32_16x16x32_f16(a1, b1, acc11, 0, 0, 0);
  }

  // C/D layout (m89-verified): col = lane&15, row = (lane>>4)*4 + reg
  #pragma unroll
  for (int fi = 0; fi < 2; ++fi) {
    #pragma unroll
    for (int fj = 0; fj < 2; ++fj) {
      const f32x4 acc = (fi == 0) ? (fj == 0 ? acc00 : acc01)
                                  : (fj == 0 ? acc10 : acc11);
      #pragma unroll
      for (int rr = 0; rr < 4; ++rr)
        red[wid][16*fi + 4*kg + rr][16*fj + r16] = acc[rr];
    }
  }
  __syncthreads();

  const int row = tid >> 3;
  const int c4  = (tid & 7) * 4;
  const float* biasp = (j0 < D_H) ? (bh + j0) : (bm + (j0 - D_H));
  float4 bias = *(const float4*)(biasp + c4);
  float4 o;
  #pragma unroll
  for (int q = 0; q < 4; ++q) {
    float s = red[0][row][c4+q] + red[1][row][c4+q]
            + red[2][row][c4+q] + red[3][row][c4+q];
    float x = (s + (&bias.x)[q]) * L2E2;
    x = fminf(fmaxf(x, -ECLAMP), ECLAMP);
    (&o.x)[q] = __builtin_amdgcn_exp2f(x);
  }
  *(float4*)(C + (size_t)(i0 + row) * 1024 + j0 + c4) = o;
}

// ---------------------------------------------------------------------------
// proj fallback (fp32 vector GEMM) when ws is too small for f16 staging.
// ---------------------------------------------------------------------------
__global__ __launch_bounds__(256) void proj_kernel(
    const float* __restrict__ V,
    const float* __restrict__ Wh, const float* __restrict__ bh,
    const float* __restrict__ Wm, const float* __restrict__ bm,
    float* __restrict__ C)
{
  __shared__ float As[16][68];
  __shared__ float Bs[16][68];

  const int tid = threadIdx.x;
  const int i0  = (blockIdx.x & 15) * 64, j0 = (blockIdx.x >> 4) * 64;
  const int ti  = tid >> 4, tj = tid & 15;
  const int sr  = tid >> 2;
  const int sk  = (tid & 3) << 2;

  const float* Wbase = (j0 < D_H) ? (Wh + (size_t)j0 * D_IN)
                                  : (Wm + (size_t)(j0 - D_H) * D_IN);
  const float* biasp = (j0 < D_H) ? (bh + j0) : (bm + (j0 - D_H));

  const float* arow = V     + (size_t)(i0 + sr) * D_IN + sk;
  const float* brow = Wbase + (size_t)sr        * D_IN + sk;

  float acc[4][4] = {};
  for (int k0 = 0; k0 < D_IN; k0 += 16) {
    float4 av = *(const float4*)(arow + k0);
    float4 bv = *(const float4*)(brow + k0);
    As[sk+0][sr] = av.x; As[sk+1][sr] = av.y; As[sk+2][sr] = av.z; As[sk+3][sr] = av.w;
    Bs[sk+0][sr] = bv.x; Bs[sk+1][sr] = bv.y; Bs[sk+2][sr] = bv.z; Bs[sk+3][sr] = bv.w;
    __syncthreads();
    #pragma unroll
    for (int kk = 0; kk < 16; ++kk) {
      float4 a = *(const float4*)&As[kk][4*ti];
      float4 b = *(const float4*)&Bs[kk][4*tj];
      #pragma unroll
      for (int x = 0; x < 4; ++x)
        #pragma unroll
        for (int y = 0; y < 4; ++y)
          acc[x][y] = fmaf((&a.x)[x], (&b.x)[y], acc[x][y]);
    }
    __syncthreads();
  }

  const int jl = 4 * tj;
  #pragma unroll
  for (int aa = 0; aa < 4; ++aa) {
    const int i = i0 + 4*ti + aa;
    float4 o;
    #pragma unroll
    for (int bb = 0; bb < 4; ++bb) {
      float x = (acc[aa][bb] + biasp[jl+bb]) * L2E2;
      x = fminf(fmaxf(x, -ECLAMP), ECLAMP);
      (&o.x)[bb] = __builtin_amdgcn_exp2f(x);
    }
    *(float4*)(C + (size_t)i * 1024 + j0 + jl) = o;
  }
}

// ---------------------------------------------------------------------------
// score_h: HYBRID score. 64x64 tile, 4x4/thread, K-quarter per block
// (grid 1024). em staged in LDS (whole quarter at once, ms[64][132] = 34KB,
// ONE barrier); eh read directly from global as 16-lane-broadcast float4s
// (4 rows/wave, 64B lines amortized over 4 groups -> L1-friendly; R16
// proved eh-pattern fine / em-pattern toxic). LDS traffic halves vs R13:
// 4 b128/group. w2 via s_load (R13-proven; R17's wls spilled). Partials
// stored as f16 planes; kh=0 plane carries base. XCD swizzle.
// ---------------------------------------------------------------------------
__global__ __launch_bounds__(256, 2) void score_h_kernel(
    const float* __restrict__ C,
    const float* __restrict__ w2,
    const float* __restrict__ b2,
    _Float16* __restrict__ P0, _Float16* __restrict__ P1,
    _Float16* __restrict__ P2, _Float16* __restrict__ P3)
{
  __shared__ float ms[64][132];     // whole quarter's Em tile (stride===36 mod 32)
  __shared__ float wred[4];

  const int tid  = threadIdx.x;
  const int b    = blockIdx.x;
  const int v    = (b & 7) * 128 + (b >> 3);   // XCD-grouped virtual id
  const int tile = v >> 2;
  const int kh   = v & 3;
  const int i0   = (tile & 15) * 64;
  const int j0   = (tile >> 4) * 64;
  const int kb   = kh * 128;
  const int ti   = tid >> 4, tj = tid & 15;    // outputs: i0+ti+16a, j0+tj+16c

  if (kh == 0) {            // block-uniform branch
    float sw = 0.f;
    for (int t = tid; t < D_H; t += 256) sw += w2[t];
    #pragma unroll
    for (int off = 32; off > 0; off >>= 1) sw += __shfl_down(sw, off, 64);
    if ((tid & 63) == 0) wred[tid >> 6] = sw;
  }

  // stage whole quarter of Em: 2048 float4s, 8 per thread
  #pragma unroll
  for (int s = 0; s < 8; ++s) {
    const int idx = tid + 256 * s;       // 0..2047
    const int row = idx >> 5;            // 0..63
    const int c4  = (idx & 31) << 2;     // 0..124
    float4 mv = *(const float4*)(C + (size_t)(j0 + row) * 1024 + D_H + kb + c4);
    *(float4*)&ms[row][c4] = mv;
  }
  __syncthreads();          // the only barrier (also covers wred)

  const float* ehb = C + (size_t)(i0 + ti) * 1024 + kb;   // +a*16*1024 + k

  float acc[4][4] = {};

  #pragma unroll 8
  for (int g = 0; g < 32; ++g) {
    const int kk = 4 * g;
    float4 eh[4], em[4];
    #pragma unroll
    for (int a = 0; a < 4; ++a)
      eh[a] = *(const float4*)(ehb + (size_t)a * 16384 + kk);   // broadcast global
    #pragma unroll
    for (int c = 0; c < 4; ++c)
      em[c] = *(const float4*)&ms[tj + 16*c][kk];               // LDS

    const float wA = w2[kb + kk + 0];
    const float wB = w2[kb + kk + 1];
    const float wC = w2[kb + kk + 2];
    const float wD = w2[kb + kk + 3];
    #pragma unroll
    for (int a = 0; a < 4; ++a) {
      #pragma unroll
      for (int c = 0; c < 4; ++c) {
        float uA = fmaf(eh[a].x, em[c].x, 1.f);
        float uB = fmaf(eh[a].y, em[c].y, 1.f);
        float uC = fmaf(eh[a].z, em[c].z, 1.f);
        float uD = fmaf(eh[a].w, em[c].w, 1.f);
        float dAB = uA * uB, dCD = uC * uD;
        float nAB = fmaf(wB, uA, wA * uB);
        float nCD = fmaf(wD, uC, wC * uD);
        float den = dAB * dCD;
        float num = fmaf(nCD, dAB, nAB * dCD);
        acc[a][c] = fmaf(num, __builtin_amdgcn_rcpf(den), acc[a][c]);
      }
    }
  }

  float base = 0.f;
  if (kh == 0) base = b2[0] + wred[0] + wred[1] + wred[2] + wred[3];
  _Float16* Pz = (kh == 0) ? P0 : (kh == 1) ? P1 : (kh == 2) ? P2 : P3;
  #pragma unroll
  for (int a = 0; a < 4; ++a) {
    const int i = i0 + ti + 16*a;
    #pragma unroll
    for (int c = 0; c < 4; ++c) {
      const int j = j0 + tj + 16*c;
      Pz[(size_t)i * 1024 + j] = (_Float16)fmaf(-2.f, acc[a][c], base);
    }
  }
}

// combine: out = P0 + P1 + P2 + P3 (f16 planes -> f32)
__global__ __launch_bounds__(256) void combine_kernel(
    const _Float16* __restrict__ P0, const _Float16* __restrict__ P1,
    const _Float16* __restrict__ P2, const _Float16* __restrict__ P3,
    float* __restrict__ out)
{
  const int idx = blockIdx.x * 256 + threadIdx.x;   // 0..262143 quads
  half4v a = ((const half4v*)P0)[idx];
  half4v b = ((const half4v*)P1)[idx];
  half4v c = ((const half4v*)P2)[idx];
  half4v d = ((const half4v*)P3)[idx];
  float4 o;
  #pragma unroll
  for (int q = 0; q < 4; ++q)
    (&o.x)[q] = (float)a[q] + (float)b[q] + ((float)c[q] + (float)d[q]);
  ((float4*)out)[idx] = o;
}

// ---------------------------------------------------------------------------
// score fallback (R9/R13 structure, proven): 64x32 tile, 4x2/thread, grid 512.
// ---------------------------------------------------------------------------
__global__ __launch_bounds__(256, 2) void score_kernel_r9(
    const float* __restrict__ C,
    const float* __restrict__ w2,
    const float* __restrict__ b2,
    float* __restrict__ out)
{
  __shared__ float hs[2][64][36];
  __shared__ float ms[2][32][36];
  __shared__ float wred[4];

  const int tid = threadIdx.x;
  const int bi  = blockIdx.x & 15;
  const int bj  = blockIdx.x >> 4;
  const int i0  = bi * 64, j0 = bj * 32;
  const int ti  = tid >> 4, tj = tid & 15;

  const int sr  = tid >> 3;
  const int sk  = (tid & 7) << 2;

  float sw = 0.f;
  for (int t = tid; t < D_H; t += 256) sw += w2[t];
  #pragma unroll
  for (int off = 32; off > 0; off >>= 1) sw += __shfl_down(sw, off, 64);
  if ((tid & 63) == 0) wred[tid >> 6] = sw;

  const float* hrow0 = C + (size_t)(i0 + sr)      * 1024 + sk;
  const float* hrow1 = C + (size_t)(i0 + sr + 32) * 1024 + sk;
  const float* mrow  = C + (size_t)(j0 + sr) * 1024 + D_H + sk;

  float4 hv0 = *(const float4*)(hrow0);
  float4 hv1 = *(const float4*)(hrow1);
  float4 mv  = *(const float4*)(mrow);

  float acc[4][2] = {};
  int p = 0;

  for (int k0 = 0; k0 < D_H; k0 += 32) {
    *(float4*)&hs[p][sr][sk]      = hv0;
    *(float4*)&hs[p][sr + 32][sk] = hv1;
    *(float4*)&ms[p][sr][sk]      = mv;
    __syncthreads();

    if (k0 + 32 < D_H) {
      hv0 = *(const float4*)(hrow0 + k0 + 32);
      hv1 = *(const float4*)(hrow1 + k0 + 32);
      mv  = *(const float4*)(mrow  + k0 + 32);
    }

    #pragma unroll
    for (int g = 0; g < 8; ++g) {
      const int kk = 4 * g;
      float4 eh[4];
      float4 em[2];
      #pragma unroll
      for (int a = 0; a < 4; ++a)
        eh[a] = *(const float4*)&hs[p][ti + 16*a][kk];
      #pragma unroll
      for (int c = 0; c < 2; ++c)
        em[c] = *(const float4*)&ms[p][tj + 16*c][kk];

      const float wA = w2[k0 + kk + 0];
      const float wB = w2[k0 + kk + 1];
      const float wC = w2[k0 + kk + 2];
      const float wD = w2[k0 + kk + 3];
      #pragma unroll
      for (int a = 0; a < 4; ++a) {
        #pragma unroll
        for (int c = 0; c < 2; ++c) {
          float uA = fmaf(eh[a].x, em[c].x, 1.f);
          float uB = fmaf(eh[a].y, em[c].y, 1.f);
          float uC = fmaf(eh[a].z, em[c].z, 1.f);
          float uD = fmaf(eh[a].w, em[c].w, 1.f);
          float dAB = uA * uB, dCD = uC * uD;
          float nAB = fmaf(wB, uA, wA * uB);
          float nCD = fmaf(wD, uC, wC * uD);
          float den = dAB * dCD;
          float num = fmaf(nCD, dAB, nAB * dCD);
          acc[a][c] = fmaf(num, __builtin_amdgcn_rcpf(den), acc[a][c]);
        }
      }
    }
    p ^= 1;
  }

  const float base = b2[0] + wred[0] + wred[1] + wred[2] + wred[3];
  #pragma unroll
  for (int a = 0; a < 4; ++a) {
    const int i = i0 + ti + 16*a;
    #pragma unroll
    for (int c = 0; c < 2; ++c) {
      const int j = j0 + tj + 16*c;
      out[(size_t)i * 1024 + j] = fmaf(-2.f, acc[a][c], base);
    }
  }
}

extern "C" void kernel_launch(void* const* d_in, const int* in_sizes, int n_in,
                              void* d_out, int out_size, void* d_ws, size_t ws_size,
                              hipStream_t stream) {
  const float* V  = (const float*)d_in[0];
  const float* Wh = (const float*)d_in[1];
  const float* bh = (const float*)d_in[2];
  const float* Wm = (const float*)d_in[3];
  const float* bm = (const float*)d_in[4];
  const float* w2 = (const float*)d_in[5];
  const float* b2 = (const float*)d_in[6];
  float* outp = (float*)d_out;

  char* ws = (char*)d_ws;
  float* C = (float*)ws;                                 // 4 MB: Eh|Em

  if (ws_size >= (size_t)(16u << 20)) {
    _Float16* Vh = (_Float16*)(ws + (4u << 20));         // 2 MB
    _Float16* Wf = (_Float16*)(ws + (6u << 20));         // 2 MB
    _Float16* P0 = (_Float16*)(ws + (8u << 20));         // 2 MB each
    _Float16* P1 = (_Float16*)(ws + (10u << 20));
    _Float16* P2 = (_Float16*)(ws + (12u << 20));
    _Float16* P3 = (_Float16*)(ws + (14u << 20));
    cvt_kernel<<<dim3(1024), dim3(256), 0, stream>>>(V, Wh, Wm, Vh, Wf);
    proj_mfma_kernel<<<dim3(1024), dim3(256), 0, stream>>>(Vh, Wf, bh, bm, C);
    score_h_kernel<<<dim3(1024), dim3(256), 0, stream>>>(C, w2, b2, P0, P1, P2, P3);
    combine_kernel<<<dim3(1024), dim3(256), 0, stream>>>(P0, P1, P2, P3, outp);
  } else if (ws_size >= (size_t)(8u << 20)) {
    _Float16* Vh = (_Float16*)(ws + (4u << 20));         // 2 MB
    _Float16* Wf = (_Float16*)(ws + (6u << 20));         // 2 MB
    cvt_kernel<<<dim3(1024), dim3(256), 0, stream>>>(V, Wh, Wm, Vh, Wf);
    proj_mfma_kernel<<<dim3(1024), dim3(256), 0, stream>>>(Vh, Wf, bh, bm, C);
    score_kernel_r9<<<dim3(512), dim3(256), 0, stream>>>(C, w2, b2, outp);
  } else {
    proj_kernel<<<dim3(256), dim3(256), 0, stream>>>(V, Wh, bh, Wm, bm, C);
    score_kernel_r9<<<dim3(512), dim3(256), 0, stream>>>(C, w2, b2, outp);
  }
}

// Round 19
// 76.689 us; speedup vs baseline: 1.3786x; 1.0097x over previous
//
#include <hip/hip_runtime.h>
#include <hip/hip_bf16.h>

#define D_IN  1024
#define D_H   512
#define L2E2  2.885390081777927f   // 2*log2(e)
#define ECLAMP 15.0f               // exp2-arg clamp: e in [2^-15, 2^15]

typedef _Float16 half8 __attribute__((ext_vector_type(8)));
typedef _Float16 half4v __attribute__((ext_vector_type(4)));
typedef float f32x4 __attribute__((ext_vector_type(4)));

// ---------------------------------------------------------------------------
// cvt: V (1024x1024 f32) -> Vh f16 ; [Wh;Wm] (1024x1024 f32) -> Wf f16
// ---------------------------------------------------------------------------
__global__ __launch_bounds__(256) void cvt_kernel(
    const float* __restrict__ V,
    const float* __restrict__ Wh, const float* __restrict__ Wm,
    _Float16* __restrict__ Vh, _Float16* __restrict__ Wf)
{
  const int idx = blockIdx.x * 256 + threadIdx.x;   // 0..262143 float4s
  {
    float4 x = ((const float4*)V)[idx];
    half4v o = { (_Float16)x.x, (_Float16)x.y, (_Float16)x.z, (_Float16)x.w };
    ((half4v*)Vh)[idx] = o;
  }
  {
    const float4* p = (idx < 131072) ? ((const float4*)Wh + idx)
                                     : ((const float4*)Wm + (idx - 131072));
    float4 x = *p;
    half4v o = { (_Float16)x.x, (_Float16)x.y, (_Float16)x.z, (_Float16)x.w };
    ((half4v*)Wf)[idx] = o;
  }
}

// ---------------------------------------------------------------------------
// proj via MFMA, k-quadrant split (R8/R13 structure): 32x32 tile, 4 waves
// each own K/4, LDS reduce, bias+exp2 epilogue. Grid 1024.
// ---------------------------------------------------------------------------
__global__ __launch_bounds__(256, 4) void proj_mfma_kernel(
    const _Float16* __restrict__ Vh, const _Float16* __restrict__ Wf,
    const float* __restrict__ bh, const float* __restrict__ bm,
    float* __restrict__ C)
{
  __shared__ float red[4][32][34];

  const int tid  = threadIdx.x;
  const int lane = tid & 63;
  const int wid  = tid >> 6;          // k-quarter 0..3
  const int bid  = blockIdx.x;
  const int swz  = (bid & 7) * 128 + (bid >> 3);
  const int i0   = (swz & 31) * 32;
  const int j0   = (swz >> 5) * 32;
  const int r16  = lane & 15;
  const int kg   = lane >> 4;         // k-group 0..3
  const int kb   = wid * 256;

  const _Float16* A0 = Vh + (size_t)(i0 + r16) * 1024 + kb + kg*8;
  const _Float16* A1 = A0 + 16 * 1024;
  const _Float16* B0 = Wf + (size_t)(j0 + r16) * 1024 + kb + kg*8;
  const _Float16* B1 = B0 + 16 * 1024;

  f32x4 acc00 = {0.f,0.f,0.f,0.f}, acc01 = acc00, acc10 = acc00, acc11 = acc00;
  #pragma unroll 4
  for (int k0 = 0; k0 < 256; k0 += 32) {
    half8 a0 = *(const half8*)(A0 + k0);
    half8 a1 = *(const half8*)(A1 + k0);
    half8 b0 = *(const half8*)(B0 + k0);
    half8 b1 = *(const half8*)(B1 + k0);
    acc00 = __builtin_amdgcn_mfma_f32_16x16x32_f16(a0, b0, acc00, 0, 0, 0);
    acc01 = __builtin_amdgcn_mfma_f32_16x16x32_f16(a0, b1, acc01, 0, 0, 0);
    acc10 = __builtin_amdgcn_mfma_f32_16x16x32_f16(a1, b0, acc10, 0, 0, 0);
    acc11 = __builtin_amdgcn_mfma_f32_16x16x32_f16(a1, b1, acc11, 0, 0, 0);
  }

  // C/D layout (m89-verified): col = lane&15, row = (lane>>4)*4 + reg
  #pragma unroll
  for (int fi = 0; fi < 2; ++fi) {
    #pragma unroll
    for (int fj = 0; fj < 2; ++fj) {
      const f32x4 acc = (fi == 0) ? (fj == 0 ? acc00 : acc01)
                                  : (fj == 0 ? acc10 : acc11);
      #pragma unroll
      for (int rr = 0; rr < 4; ++rr)
        red[wid][16*fi + 4*kg + rr][16*fj + r16] = acc[rr];
    }
  }
  __syncthreads();

  const int row = tid >> 3;
  const int c4  = (tid & 7) * 4;
  const float* biasp = (j0 < D_H) ? (bh + j0) : (bm + (j0 - D_H));
  float4 bias = *(const float4*)(biasp + c4);
  float4 o;
  #pragma unroll
  for (int q = 0; q < 4; ++q) {
    float s = red[0][row][c4+q] + red[1][row][c4+q]
            + red[2][row][c4+q] + red[3][row][c4+q];
    float x = (s + (&bias.x)[q]) * L2E2;
    x = fminf(fmaxf(x, -ECLAMP), ECLAMP);
    (&o.x)[q] = __builtin_amdgcn_exp2f(x);
  }
  *(float4*)(C + (size_t)(i0 + row) * 1024 + j0 + c4) = o;
}

// ---------------------------------------------------------------------------
// proj fallback (fp32 vector GEMM) when ws is too small for f16 staging.
// ---------------------------------------------------------------------------
__global__ __launch_bounds__(256) void proj_kernel(
    const float* __restrict__ V,
    const float* __restrict__ Wh, const float* __restrict__ bh,
    const float* __restrict__ Wm, const float* __restrict__ bm,
    float* __restrict__ C)
{
  __shared__ float As[16][68];
  __shared__ float Bs[16][68];

  const int tid = threadIdx.x;
  const int i0  = (blockIdx.x & 15) * 64, j0 = (blockIdx.x >> 4) * 64;
  const int ti  = tid >> 4, tj = tid & 15;
  const int sr  = tid >> 2;
  const int sk  = (tid & 3) << 2;

  const float* Wbase = (j0 < D_H) ? (Wh + (size_t)j0 * D_IN)
                                  : (Wm + (size_t)(j0 - D_H) * D_IN);
  const float* biasp = (j0 < D_H) ? (bh + j0) : (bm + (j0 - D_H));

  const float* arow = V     + (size_t)(i0 + sr) * D_IN + sk;
  const float* brow = Wbase + (size_t)sr        * D_IN + sk;

  float acc[4][4] = {};
  for (int k0 = 0; k0 < D_IN; k0 += 16) {
    float4 av = *(const float4*)(arow + k0);
    float4 bv = *(const float4*)(brow + k0);
    As[sk+0][sr] = av.x; As[sk+1][sr] = av.y; As[sk+2][sr] = av.z; As[sk+3][sr] = av.w;
    Bs[sk+0][sr] = bv.x; Bs[sk+1][sr] = bv.y; Bs[sk+2][sr] = bv.z; Bs[sk+3][sr] = bv.w;
    __syncthreads();
    #pragma unroll
    for (int kk = 0; kk < 16; ++kk) {
      float4 a = *(const float4*)&As[kk][4*ti];
      float4 b = *(const float4*)&Bs[kk][4*tj];
      #pragma unroll
      for (int x = 0; x < 4; ++x)
        #pragma unroll
        for (int y = 0; y < 4; ++y)
          acc[x][y] = fmaf((&a.x)[x], (&b.x)[y], acc[x][y]);
    }
    __syncthreads();
  }

  const int jl = 4 * tj;
  #pragma unroll
  for (int aa = 0; aa < 4; ++aa) {
    const int i = i0 + 4*ti + aa;
    float4 o;
    #pragma unroll
    for (int bb = 0; bb < 4; ++bb) {
      float x = (acc[aa][bb] + biasp[jl+bb]) * L2E2;
      x = fminf(fmaxf(x, -ECLAMP), ECLAMP);
      (&o.x)[bb] = __builtin_amdgcn_exp2f(x);
    }
    *(float4*)(C + (size_t)i * 1024 + j0 + jl) = o;
  }
}

// ---------------------------------------------------------------------------
// score_h (R18 hybrid + 8-way k-fold): 64x64 tile, 4x4/thread, K-quarter
// per block (grid 1024). em in LDS (whole quarter, one barrier); eh via
// broadcast global loads; w2 via s_load. 8-way fold: num8/den8 combine two
// 4-blocks -> ONE rcp per 8 k per output (30 VALU + 1 rcp vs 28 + 2).
// Range: den8 <= 2^120 < f32 max. Partials f16 planes; kh=0 carries base.
// ---------------------------------------------------------------------------
__global__ __launch_bounds__(256, 2) void score_h_kernel(
    const float* __restrict__ C,
    const float* __restrict__ w2,
    const float* __restrict__ b2,
    _Float16* __restrict__ P0, _Float16* __restrict__ P1,
    _Float16* __restrict__ P2, _Float16* __restrict__ P3)
{
  __shared__ float ms[64][132];     // whole quarter's Em tile (stride===36 mod 32)
  __shared__ float wred[4];

  const int tid  = threadIdx.x;
  const int b    = blockIdx.x;
  const int v    = (b & 7) * 128 + (b >> 3);   // XCD-grouped virtual id
  const int tile = v >> 2;
  const int kh   = v & 3;
  const int i0   = (tile & 15) * 64;
  const int j0   = (tile >> 4) * 64;
  const int kb   = kh * 128;
  const int ti   = tid >> 4, tj = tid & 15;    // outputs: i0+ti+16a, j0+tj+16c

  if (kh == 0) {            // block-uniform branch
    float sw = 0.f;
    for (int t = tid; t < D_H; t += 256) sw += w2[t];
    #pragma unroll
    for (int off = 32; off > 0; off >>= 1) sw += __shfl_down(sw, off, 64);
    if ((tid & 63) == 0) wred[tid >> 6] = sw;
  }

  // stage whole quarter of Em: 2048 float4s, 8 per thread
  #pragma unroll
  for (int s = 0; s < 8; ++s) {
    const int idx = tid + 256 * s;       // 0..2047
    const int row = idx >> 5;            // 0..63
    const int c4  = (idx & 31) << 2;     // 0..124
    float4 mv = *(const float4*)(C + (size_t)(j0 + row) * 1024 + D_H + kb + c4);
    *(float4*)&ms[row][c4] = mv;
  }
  __syncthreads();          // the only barrier (also covers wred)

  const float* ehb = C + (size_t)(i0 + ti) * 1024 + kb;   // +a*16*1024 + k

  float acc[4][4] = {};

  #pragma unroll 4
  for (int g = 0; g < 16; ++g) {        // 16 groups of 8 k
    const int kk = 8 * g;
    float4 eh0[4], eh1[4], em0[4], em1[4];
    #pragma unroll
    for (int a = 0; a < 4; ++a) {
      eh0[a] = *(const float4*)(ehb + (size_t)a * 16384 + kk);
      eh1[a] = *(const float4*)(ehb + (size_t)a * 16384 + kk + 4);
    }
    #pragma unroll
    for (int c = 0; c < 4; ++c) {
      em0[c] = *(const float4*)&ms[tj + 16*c][kk];
      em1[c] = *(const float4*)&ms[tj + 16*c][kk + 4];
    }

    const float wA = w2[kb + kk + 0];
    const float wB = w2[kb + kk + 1];
    const float wC = w2[kb + kk + 2];
    const float wD = w2[kb + kk + 3];
    const float wE = w2[kb + kk + 4];
    const float wF = w2[kb + kk + 5];
    const float wG = w2[kb + kk + 6];
    const float wH = w2[kb + kk + 7];
    #pragma unroll
    for (int a = 0; a < 4; ++a) {
      #pragma unroll
      for (int c = 0; c < 4; ++c) {
        // first 4-block
        float uA = fmaf(eh0[a].x, em0[c].x, 1.f);
        float uB = fmaf(eh0[a].y, em0[c].y, 1.f);
        float uC = fmaf(eh0[a].z, em0[c].z, 1.f);
        float uD = fmaf(eh0[a].w, em0[c].w, 1.f);
        float dAB = uA * uB, dCD = uC * uD;
        float nAB = fmaf(wB, uA, wA * uB);
        float nCD = fmaf(wD, uC, wC * uD);
        float den1 = dAB * dCD;
        float num1 = fmaf(nCD, dAB, nAB * dCD);
        // second 4-block
        float uE = fmaf(eh1[a].x, em1[c].x, 1.f);
        float uF = fmaf(eh1[a].y, em1[c].y, 1.f);
        float uG = fmaf(eh1[a].z, em1[c].z, 1.f);
        float uH = fmaf(eh1[a].w, em1[c].w, 1.f);
        float dEF = uE * uF, dGH = uG * uH;
        float nEF = fmaf(wF, uE, wE * uF);
        float nGH = fmaf(wH, uG, wG * uH);
        float den2 = dEF * dGH;
        float num2 = fmaf(nGH, dEF, nEF * dGH);
        // combine: one rcp per 8 k
        float den = den1 * den2;
        float num = fmaf(num2, den1, num1 * den2);
        acc[a][c] = fmaf(num, __builtin_amdgcn_rcpf(den), acc[a][c]);
      }
    }
  }

  float base = 0.f;
  if (kh == 0) base = b2[0] + wred[0] + wred[1] + wred[2] + wred[3];
  _Float16* Pz = (kh == 0) ? P0 : (kh == 1) ? P1 : (kh == 2) ? P2 : P3;
  #pragma unroll
  for (int a = 0; a < 4; ++a) {
    const int i = i0 + ti + 16*a;
    #pragma unroll
    for (int c = 0; c < 4; ++c) {
      const int j = j0 + tj + 16*c;
      Pz[(size_t)i * 1024 + j] = (_Float16)fmaf(-2.f, acc[a][c], base);
    }
  }
}

// combine: out = P0 + P1 + P2 + P3 (f16 planes -> f32)
__global__ __launch_bounds__(256) void combine_kernel(
    const _Float16* __restrict__ P0, const _Float16* __restrict__ P1,
    const _Float16* __restrict__ P2, const _Float16* __restrict__ P3,
    float* __restrict__ out)
{
  const int idx = blockIdx.x * 256 + threadIdx.x;   // 0..262143 quads
  half4v a = ((const half4v*)P0)[idx];
  half4v b = ((const half4v*)P1)[idx];
  half4v c = ((const half4v*)P2)[idx];
  half4v d = ((const half4v*)P3)[idx];
  float4 o;
  #pragma unroll
  for (int q = 0; q < 4; ++q)
    (&o.x)[q] = (float)a[q] + (float)b[q] + ((float)c[q] + (float)d[q]);
  ((float4*)out)[idx] = o;
}

// ---------------------------------------------------------------------------
// score fallback (R9/R13 structure, proven): 64x32 tile, 4x2/thread, grid 512.
// ---------------------------------------------------------------------------
__global__ __launch_bounds__(256, 2) void score_kernel_r9(
    const float* __restrict__ C,
    const float* __restrict__ w2,
    const float* __restrict__ b2,
    float* __restrict__ out)
{
  __shared__ float hs[2][64][36];
  __shared__ float ms[2][32][36];
  __shared__ float wred[4];

  const int tid = threadIdx.x;
  const int bi  = blockIdx.x & 15;
  const int bj  = blockIdx.x >> 4;
  const int i0  = bi * 64, j0 = bj * 32;
  const int ti  = tid >> 4, tj = tid & 15;

  const int sr  = tid >> 3;
  const int sk  = (tid & 7) << 2;

  float sw = 0.f;
  for (int t = tid; t < D_H; t += 256) sw += w2[t];
  #pragma unroll
  for (int off = 32; off > 0; off >>= 1) sw += __shfl_down(sw, off, 64);
  if ((tid & 63) == 0) wred[tid >> 6] = sw;

  const float* hrow0 = C + (size_t)(i0 + sr)      * 1024 + sk;
  const float* hrow1 = C + (size_t)(i0 + sr + 32) * 1024 + sk;
  const float* mrow  = C + (size_t)(j0 + sr) * 1024 + D_H + sk;

  float4 hv0 = *(const float4*)(hrow0);
  float4 hv1 = *(const float4*)(hrow1);
  float4 mv  = *(const float4*)(mrow);

  float acc[4][2] = {};
  int p = 0;

  for (int k0 = 0; k0 < D_H; k0 += 32) {
    *(float4*)&hs[p][sr][sk]      = hv0;
    *(float4*)&hs[p][sr + 32][sk] = hv1;
    *(float4*)&ms[p][sr][sk]      = mv;
    __syncthreads();

    if (k0 + 32 < D_H) {
      hv0 = *(const float4*)(hrow0 + k0 + 32);
      hv1 = *(const float4*)(hrow1 + k0 + 32);
      mv  = *(const float4*)(mrow  + k0 + 32);
    }

    #pragma unroll
    for (int g = 0; g < 8; ++g) {
      const int kk = 4 * g;
      float4 eh[4];
      float4 em[2];
      #pragma unroll
      for (int a = 0; a < 4; ++a)
        eh[a] = *(const float4*)&hs[p][ti + 16*a][kk];
      #pragma unroll
      for (int c = 0; c < 2; ++c)
        em[c] = *(const float4*)&ms[p][tj + 16*c][kk];

      const float wA = w2[k0 + kk + 0];
      const float wB = w2[k0 + kk + 1];
      const float wC = w2[k0 + kk + 2];
      const float wD = w2[k0 + kk + 3];
      #pragma unroll
      for (int a = 0; a < 4; ++a) {
        #pragma unroll
        for (int c = 0; c < 2; ++c) {
          float uA = fmaf(eh[a].x, em[c].x, 1.f);
          float uB = fmaf(eh[a].y, em[c].y, 1.f);
          float uC = fmaf(eh[a].z, em[c].z, 1.f);
          float uD = fmaf(eh[a].w, em[c].w, 1.f);
          float dAB = uA * uB, dCD = uC * uD;
          float nAB = fmaf(wB, uA, wA * uB);
          float nCD = fmaf(wD, uC, wC * uD);
          float den = dAB * dCD;
          float num = fmaf(nCD, dAB, nAB * dCD);
          acc[a][c] = fmaf(num, __builtin_amdgcn_rcpf(den), acc[a][c]);
        }
      }
    }
    p ^= 1;
  }

  const float base = b2[0] + wred[0] + wred[1] + wred[2] + wred[3];
  #pragma unroll
  for (int a = 0; a < 4; ++a) {
    const int i = i0 + ti + 16*a;
    #pragma unroll
    for (int c = 0; c < 2; ++c) {
      const int j = j0 + tj + 16*c;
      out[(size_t)i * 1024 + j] = fmaf(-2.f, acc[a][c], base);
    }
  }
}

extern "C" void kernel_launch(void* const* d_in, const int* in_sizes, int n_in,
                              void* d_out, int out_size, void* d_ws, size_t ws_size,
                              hipStream_t stream) {
  const float* V  = (const float*)d_in[0];
  const float* Wh = (const float*)d_in[1];
  const float* bh = (const float*)d_in[2];
  const float* Wm = (const float*)d_in[3];
  const float* bm = (const float*)d_in[4];
  const float* w2 = (const float*)d_in[5];
  const float* b2 = (const float*)d_in[6];
  float* outp = (float*)d_out;

  char* ws = (char*)d_ws;
  float* C = (float*)ws;                                 // 4 MB: Eh|Em

  if (ws_size >= (size_t)(16u << 20)) {
    _Float16* Vh = (_Float16*)(ws + (4u << 20));         // 2 MB
    _Float16* Wf = (_Float16*)(ws + (6u << 20));         // 2 MB
    _Float16* P0 = (_Float16*)(ws + (8u << 20));         // 2 MB each
    _Float16* P1 = (_Float16*)(ws + (10u << 20));
    _Float16* P2 = (_Float16*)(ws + (12u << 20));
    _Float16* P3 = (_Float16*)(ws + (14u << 20));
    cvt_kernel<<<dim3(1024), dim3(256), 0, stream>>>(V, Wh, Wm, Vh, Wf);
    proj_mfma_kernel<<<dim3(1024), dim3(256), 0, stream>>>(Vh, Wf, bh, bm, C);
    score_h_kernel<<<dim3(1024), dim3(256), 0, stream>>>(C, w2, b2, P0, P1, P2, P3);
    combine_kernel<<<dim3(1024), dim3(256), 0, stream>>>(P0, P1, P2, P3, outp);
  } else if (ws_size >= (size_t)(8u << 20)) {
    _Float16* Vh = (_Float16*)(ws + (4u << 20));         // 2 MB
    _Float16* Wf = (_Float16*)(ws + (6u << 20));         // 2 MB
    cvt_kernel<<<dim3(1024), dim3(256), 0, stream>>>(V, Wh, Wm, Vh, Wf);
    proj_mfma_kernel<<<dim3(1024), dim3(256), 0, stream>>>(Vh, Wf, bh, bm, C);
    score_kernel_r9<<<dim3(512), dim3(256), 0, stream>>>(C, w2, b2, outp);
  } else {
    proj_kernel<<<dim3(256), dim3(256), 0, stream>>>(V, Wh, bh, Wm, bm, C);
    score_kernel_r9<<<dim3(512), dim3(256), 0, stream>>>(C, w2, b2, outp);
  }
}

// Round 20
// 76.016 us; speedup vs baseline: 1.3908x; 1.0089x over previous
//
#include <hip/hip_runtime.h>
#include <hip/hip_bf16.h>

#define D_IN  1024
#define D_H   512
#define L2E2  2.885390081777927f   // 2*log2(e)
#define ECLAMP 15.0f               // exp2-arg clamp: e in [2^-15, 2^15]

typedef _Float16 half8 __attribute__((ext_vector_type(8)));
typedef _Float16 half4v __attribute__((ext_vector_type(4)));
typedef float f32x4 __attribute__((ext_vector_type(4)));

// ---------------------------------------------------------------------------
// cvt: V (1024x1024 f32) -> Vh f16 ; [Wh;Wm] (1024x1024 f32) -> Wf f16
// ---------------------------------------------------------------------------
__global__ __launch_bounds__(256) void cvt_kernel(
    const float* __restrict__ V,
    const float* __restrict__ Wh, const float* __restrict__ Wm,
    _Float16* __restrict__ Vh, _Float16* __restrict__ Wf)
{
  const int idx = blockIdx.x * 256 + threadIdx.x;   // 0..262143 float4s
  {
    float4 x = ((const float4*)V)[idx];
    half4v o = { (_Float16)x.x, (_Float16)x.y, (_Float16)x.z, (_Float16)x.w };
    ((half4v*)Vh)[idx] = o;
  }
  {
    const float4* p = (idx < 131072) ? ((const float4*)Wh + idx)
                                     : ((const float4*)Wm + (idx - 131072));
    float4 x = *p;
    half4v o = { (_Float16)x.x, (_Float16)x.y, (_Float16)x.z, (_Float16)x.w };
    ((half4v*)Wf)[idx] = o;
  }
}

// ---------------------------------------------------------------------------
// proj via MFMA, k-quadrant split (R8/R13 structure): 32x32 tile, 4 waves
// each own K/4, LDS reduce, bias+exp2 epilogue. Grid 1024.
// FULL unroll (8 k-steps): 32 fragment loads in flight (L2-latency-bound).
// ---------------------------------------------------------------------------
__global__ __launch_bounds__(256, 4) void proj_mfma_kernel(
    const _Float16* __restrict__ Vh, const _Float16* __restrict__ Wf,
    const float* __restrict__ bh, const float* __restrict__ bm,
    float* __restrict__ C)
{
  __shared__ float red[4][32][34];

  const int tid  = threadIdx.x;
  const int lane = tid & 63;
  const int wid  = tid >> 6;          // k-quarter 0..3
  const int bid  = blockIdx.x;
  const int swz  = (bid & 7) * 128 + (bid >> 3);
  const int i0   = (swz & 31) * 32;
  const int j0   = (swz >> 5) * 32;
  const int r16  = lane & 15;
  const int kg   = lane >> 4;         // k-group 0..3
  const int kb   = wid * 256;

  const _Float16* A0 = Vh + (size_t)(i0 + r16) * 1024 + kb + kg*8;
  const _Float16* A1 = A0 + 16 * 1024;
  const _Float16* B0 = Wf + (size_t)(j0 + r16) * 1024 + kb + kg*8;
  const _Float16* B1 = B0 + 16 * 1024;

  f32x4 acc00 = {0.f,0.f,0.f,0.f}, acc01 = acc00, acc10 = acc00, acc11 = acc00;
  #pragma unroll 8
  for (int k0 = 0; k0 < 256; k0 += 32) {
    half8 a0 = *(const half8*)(A0 + k0);
    half8 a1 = *(const half8*)(A1 + k0);
    half8 b0 = *(const half8*)(B0 + k0);
    half8 b1 = *(const half8*)(B1 + k0);
    acc00 = __builtin_amdgcn_mfma_f32_16x16x32_f16(a0, b0, acc00, 0, 0, 0);
    acc01 = __builtin_amdgcn_mfma_f32_16x16x32_f16(a0, b1, acc01, 0, 0, 0);
    acc10 = __builtin_amdgcn_mfma_f32_16x16x32_f16(a1, b0, acc10, 0, 0, 0);
    acc11 = __builtin_amdgcn_mfma_f32_16x16x32_f16(a1, b1, acc11, 0, 0, 0);
  }

  // C/D layout (m89-verified): col = lane&15, row = (lane>>4)*4 + reg
  #pragma unroll
  for (int fi = 0; fi < 2; ++fi) {
    #pragma unroll
    for (int fj = 0; fj < 2; ++fj) {
      const f32x4 acc = (fi == 0) ? (fj == 0 ? acc00 : acc01)
                                  : (fj == 0 ? acc10 : acc11);
      #pragma unroll
      for (int rr = 0; rr < 4; ++rr)
        red[wid][16*fi + 4*kg + rr][16*fj + r16] = acc[rr];
    }
  }
  __syncthreads();

  const int row = tid >> 3;
  const int c4  = (tid & 7) * 4;
  const float* biasp = (j0 < D_H) ? (bh + j0) : (bm + (j0 - D_H));
  float4 bias = *(const float4*)(biasp + c4);
  float4 o;
  #pragma unroll
  for (int q = 0; q < 4; ++q) {
    float s = red[0][row][c4+q] + red[1][row][c4+q]
            + red[2][row][c4+q] + red[3][row][c4+q];
    float x = (s + (&bias.x)[q]) * L2E2;
    x = fminf(fmaxf(x, -ECLAMP), ECLAMP);
    (&o.x)[q] = __builtin_amdgcn_exp2f(x);
  }
  *(float4*)(C + (size_t)(i0 + row) * 1024 + j0 + c4) = o;
}

// ---------------------------------------------------------------------------
// proj fallback (fp32 vector GEMM) when ws is too small for f16 staging.
// ---------------------------------------------------------------------------
__global__ __launch_bounds__(256) void proj_kernel(
    const float* __restrict__ V,
    const float* __restrict__ Wh, const float* __restrict__ bh,
    const float* __restrict__ Wm, const float* __restrict__ bm,
    float* __restrict__ C)
{
  __shared__ float As[16][68];
  __shared__ float Bs[16][68];

  const int tid = threadIdx.x;
  const int i0  = (blockIdx.x & 15) * 64, j0 = (blockIdx.x >> 4) * 64;
  const int ti  = tid >> 4, tj = tid & 15;
  const int sr  = tid >> 2;
  const int sk  = (tid & 3) << 2;

  const float* Wbase = (j0 < D_H) ? (Wh + (size_t)j0 * D_IN)
                                  : (Wm + (size_t)(j0 - D_H) * D_IN);
  const float* biasp = (j0 < D_H) ? (bh + j0) : (bm + (j0 - D_H));

  const float* arow = V     + (size_t)(i0 + sr) * D_IN + sk;
  const float* brow = Wbase + (size_t)sr        * D_IN + sk;

  float acc[4][4] = {};
  for (int k0 = 0; k0 < D_IN; k0 += 16) {
    float4 av = *(const float4*)(arow + k0);
    float4 bv = *(const float4*)(brow + k0);
    As[sk+0][sr] = av.x; As[sk+1][sr] = av.y; As[sk+2][sr] = av.z; As[sk+3][sr] = av.w;
    Bs[sk+0][sr] = bv.x; Bs[sk+1][sr] = bv.y; Bs[sk+2][sr] = bv.z; Bs[sk+3][sr] = bv.w;
    __syncthreads();
    #pragma unroll
    for (int kk = 0; kk < 16; ++kk) {
      float4 a = *(const float4*)&As[kk][4*ti];
      float4 b = *(const float4*)&Bs[kk][4*tj];
      #pragma unroll
      for (int x = 0; x < 4; ++x)
        #pragma unroll
        for (int y = 0; y < 4; ++y)
          acc[x][y] = fmaf((&a.x)[x], (&b.x)[y], acc[x][y]);
    }
    __syncthreads();
  }

  const int jl = 4 * tj;
  #pragma unroll
  for (int aa = 0; aa < 4; ++aa) {
    const int i = i0 + 4*ti + aa;
    float4 o;
    #pragma unroll
    for (int bb = 0; bb < 4; ++bb) {
      float x = (acc[aa][bb] + biasp[jl+bb]) * L2E2;
      x = fminf(fmaxf(x, -ECLAMP), ECLAMP);
      (&o.x)[bb] = __builtin_amdgcn_exp2f(x);
    }
    *(float4*)(C + (size_t)i * 1024 + j0 + jl) = o;
  }
}

// ---------------------------------------------------------------------------
// score_h (R19 structure, unroll 4->8): 64x64 tile, 4x4/thread, K-quarter
// per block (grid 1024). em in LDS (one barrier); eh via broadcast global;
// w2 via s_load; 8-way k-fold (1 rcp / 8 k / output). Deeper unroll = 2
// groups' loads in flight to bridge rcp-chain bubbles. VGPR budget: ~112
// under the (256,2)=128 cap (R11/R12-calibrated).
// ---------------------------------------------------------------------------
__global__ __launch_bounds__(256, 2) void score_h_kernel(
    const float* __restrict__ C,
    const float* __restrict__ w2,
    const float* __restrict__ b2,
    _Float16* __restrict__ P0, _Float16* __restrict__ P1,
    _Float16* __restrict__ P2, _Float16* __restrict__ P3)
{
  __shared__ float ms[64][132];     // whole quarter's Em tile (stride===36 mod 32)
  __shared__ float wred[4];

  const int tid  = threadIdx.x;
  const int b    = blockIdx.x;
  const int v    = (b & 7) * 128 + (b >> 3);   // XCD-grouped virtual id
  const int tile = v >> 2;
  const int kh   = v & 3;
  const int i0   = (tile & 15) * 64;
  const int j0   = (tile >> 4) * 64;
  const int kb   = kh * 128;
  const int ti   = tid >> 4, tj = tid & 15;    // outputs: i0+ti+16a, j0+tj+16c

  if (kh == 0) {            // block-uniform branch
    float sw = 0.f;
    for (int t = tid; t < D_H; t += 256) sw += w2[t];
    #pragma unroll
    for (int off = 32; off > 0; off >>= 1) sw += __shfl_down(sw, off, 64);
    if ((tid & 63) == 0) wred[tid >> 6] = sw;
  }

  // stage whole quarter of Em: 2048 float4s, 8 per thread
  #pragma unroll
  for (int s = 0; s < 8; ++s) {
    const int idx = tid + 256 * s;       // 0..2047
    const int row = idx >> 5;            // 0..63
    const int c4  = (idx & 31) << 2;     // 0..124
    float4 mv = *(const float4*)(C + (size_t)(j0 + row) * 1024 + D_H + kb + c4);
    *(float4*)&ms[row][c4] = mv;
  }
  __syncthreads();          // the only barrier (also covers wred)

  const float* ehb = C + (size_t)(i0 + ti) * 1024 + kb;   // +a*16*1024 + k

  float acc[4][4] = {};

  #pragma unroll 8
  for (int g = 0; g < 16; ++g) {        // 16 groups of 8 k
    const int kk = 8 * g;
    float4 eh0[4], eh1[4], em0[4], em1[4];
    #pragma unroll
    for (int a = 0; a < 4; ++a) {
      eh0[a] = *(const float4*)(ehb + (size_t)a * 16384 + kk);
      eh1[a] = *(const float4*)(ehb + (size_t)a * 16384 + kk + 4);
    }
    #pragma unroll
    for (int c = 0; c < 4; ++c) {
      em0[c] = *(const float4*)&ms[tj + 16*c][kk];
      em1[c] = *(const float4*)&ms[tj + 16*c][kk + 4];
    }

    const float wA = w2[kb + kk + 0];
    const float wB = w2[kb + kk + 1];
    const float wC = w2[kb + kk + 2];
    const float wD = w2[kb + kk + 3];
    const float wE = w2[kb + kk + 4];
    const float wF = w2[kb + kk + 5];
    const float wG = w2[kb + kk + 6];
    const float wH = w2[kb + kk + 7];
    #pragma unroll
    for (int a = 0; a < 4; ++a) {
      #pragma unroll
      for (int c = 0; c < 4; ++c) {
        // first 4-block
        float uA = fmaf(eh0[a].x, em0[c].x, 1.f);
        float uB = fmaf(eh0[a].y, em0[c].y, 1.f);
        float uC = fmaf(eh0[a].z, em0[c].z, 1.f);
        float uD = fmaf(eh0[a].w, em0[c].w, 1.f);
        float dAB = uA * uB, dCD = uC * uD;
        float nAB = fmaf(wB, uA, wA * uB);
        float nCD = fmaf(wD, uC, wC * uD);
        float den1 = dAB * dCD;
        float num1 = fmaf(nCD, dAB, nAB * dCD);
        // second 4-block
        float uE = fmaf(eh1[a].x, em1[c].x, 1.f);
        float uF = fmaf(eh1[a].y, em1[c].y, 1.f);
        float uG = fmaf(eh1[a].z, em1[c].z, 1.f);
        float uH = fmaf(eh1[a].w, em1[c].w, 1.f);
        float dEF = uE * uF, dGH = uG * uH;
        float nEF = fmaf(wF, uE, wE * uF);
        float nGH = fmaf(wH, uG, wG * uH);
        float den2 = dEF * dGH;
        float num2 = fmaf(nGH, dEF, nEF * dGH);
        // combine: one rcp per 8 k
        float den = den1 * den2;
        float num = fmaf(num2, den1, num1 * den2);
        acc[a][c] = fmaf(num, __builtin_amdgcn_rcpf(den), acc[a][c]);
      }
    }
  }

  float base = 0.f;
  if (kh == 0) base = b2[0] + wred[0] + wred[1] + wred[2] + wred[3];
  _Float16* Pz = (kh == 0) ? P0 : (kh == 1) ? P1 : (kh == 2) ? P2 : P3;
  #pragma unroll
  for (int a = 0; a < 4; ++a) {
    const int i = i0 + ti + 16*a;
    #pragma unroll
    for (int c = 0; c < 4; ++c) {
      const int j = j0 + tj + 16*c;
      Pz[(size_t)i * 1024 + j] = (_Float16)fmaf(-2.f, acc[a][c], base);
    }
  }
}

// combine: out = P0 + P1 + P2 + P3 (f16 planes -> f32)
__global__ __launch_bounds__(256) void combine_kernel(
    const _Float16* __restrict__ P0, const _Float16* __restrict__ P1,
    const _Float16* __restrict__ P2, const _Float16* __restrict__ P3,
    float* __restrict__ out)
{
  const int idx = blockIdx.x * 256 + threadIdx.x;   // 0..262143 quads
  half4v a = ((const half4v*)P0)[idx];
  half4v b = ((const half4v*)P1)[idx];
  half4v c = ((const half4v*)P2)[idx];
  half4v d = ((const half4v*)P3)[idx];
  float4 o;
  #pragma unroll
  for (int q = 0; q < 4; ++q)
    (&o.x)[q] = (float)a[q] + (float)b[q] + ((float)c[q] + (float)d[q]);
  ((float4*)out)[idx] = o;
}

// ---------------------------------------------------------------------------
// score fallback (R9/R13 structure, proven): 64x32 tile, 4x2/thread, grid 512.
// ---------------------------------------------------------------------------
__global__ __launch_bounds__(256, 2) void score_kernel_r9(
    const float* __restrict__ C,
    const float* __restrict__ w2,
    const float* __restrict__ b2,
    float* __restrict__ out)
{
  __shared__ float hs[2][64][36];
  __shared__ float ms[2][32][36];
  __shared__ float wred[4];

  const int tid = threadIdx.x;
  const int bi  = blockIdx.x & 15;
  const int bj  = blockIdx.x >> 4;
  const int i0  = bi * 64, j0 = bj * 32;
  const int ti  = tid >> 4, tj = tid & 15;

  const int sr  = tid >> 3;
  const int sk  = (tid & 7) << 2;

  float sw = 0.f;
  for (int t = tid; t < D_H; t += 256) sw += w2[t];
  #pragma unroll
  for (int off = 32; off > 0; off >>= 1) sw += __shfl_down(sw, off, 64);
  if ((tid & 63) == 0) wred[tid >> 6] = sw;

  const float* hrow0 = C + (size_t)(i0 + sr)      * 1024 + sk;
  const float* hrow1 = C + (size_t)(i0 + sr + 32) * 1024 + sk;
  const float* mrow  = C + (size_t)(j0 + sr) * 1024 + D_H + sk;

  float4 hv0 = *(const float4*)(hrow0);
  float4 hv1 = *(const float4*)(hrow1);
  float4 mv  = *(const float4*)(mrow);

  float acc[4][2] = {};
  int p = 0;

  for (int k0 = 0; k0 < D_H; k0 += 32) {
    *(float4*)&hs[p][sr][sk]      = hv0;
    *(float4*)&hs[p][sr + 32][sk] = hv1;
    *(float4*)&ms[p][sr][sk]      = mv;
    __syncthreads();

    if (k0 + 32 < D_H) {
      hv0 = *(const float4*)(hrow0 + k0 + 32);
      hv1 = *(const float4*)(hrow1 + k0 + 32);
      mv  = *(const float4*)(mrow  + k0 + 32);
    }

    #pragma unroll
    for (int g = 0; g < 8; ++g) {
      const int kk = 4 * g;
      float4 eh[4];
      float4 em[2];
      #pragma unroll
      for (int a = 0; a < 4; ++a)
        eh[a] = *(const float4*)&hs[p][ti + 16*a][kk];
      #pragma unroll
      for (int c = 0; c < 2; ++c)
        em[c] = *(const float4*)&ms[p][tj + 16*c][kk];

      const float wA = w2[k0 + kk + 0];
      const float wB = w2[k0 + kk + 1];
      const float wC = w2[k0 + kk + 2];
      const float wD = w2[k0 + kk + 3];
      #pragma unroll
      for (int a = 0; a < 4; ++a) {
        #pragma unroll
        for (int c = 0; c < 2; ++c) {
          float uA = fmaf(eh[a].x, em[c].x, 1.f);
          float uB = fmaf(eh[a].y, em[c].y, 1.f);
          float uC = fmaf(eh[a].z, em[c].z, 1.f);
          float uD = fmaf(eh[a].w, em[c].w, 1.f);
          float dAB = uA * uB, dCD = uC * uD;
          float nAB = fmaf(wB, uA, wA * uB);
          float nCD = fmaf(wD, uC, wC * uD);
          float den = dAB * dCD;
          float num = fmaf(nCD, dAB, nAB * dCD);
          acc[a][c] = fmaf(num, __builtin_amdgcn_rcpf(den), acc[a][c]);
        }
      }
    }
    p ^= 1;
  }

  const float base = b2[0] + wred[0] + wred[1] + wred[2] + wred[3];
  #pragma unroll
  for (int a = 0; a < 4; ++a) {
    const int i = i0 + ti + 16*a;
    #pragma unroll
    for (int c = 0; c < 2; ++c) {
      const int j = j0 + tj + 16*c;
      out[(size_t)i * 1024 + j] = fmaf(-2.f, acc[a][c], base);
    }
  }
}

extern "C" void kernel_launch(void* const* d_in, const int* in_sizes, int n_in,
                              void* d_out, int out_size, void* d_ws, size_t ws_size,
                              hipStream_t stream) {
  const float* V  = (const float*)d_in[0];
  const float* Wh = (const float*)d_in[1];
  const float* bh = (const float*)d_in[2];
  const float* Wm = (const float*)d_in[3];
  const float* bm = (const float*)d_in[4];
  const float* w2 = (const float*)d_in[5];
  const float* b2 = (const float*)d_in[6];
  float* outp = (float*)d_out;

  char* ws = (char*)d_ws;
  float* C = (float*)ws;                                 // 4 MB: Eh|Em

  if (ws_size >= (size_t)(16u << 20)) {
    _Float16* Vh = (_Float16*)(ws + (4u << 20));         // 2 MB
    _Float16* Wf = (_Float16*)(ws + (6u << 20));         // 2 MB
    _Float16* P0 = (_Float16*)(ws + (8u << 20));         // 2 MB each
    _Float16* P1 = (_Float16*)(ws + (10u << 20));
    _Float16* P2 = (_Float16*)(ws + (12u << 20));
    _Float16* P3 = (_Float16*)(ws + (14u << 20));
    cvt_kernel<<<dim3(1024), dim3(256), 0, stream>>>(V, Wh, Wm, Vh, Wf);
    proj_mfma_kernel<<<dim3(1024), dim3(256), 0, stream>>>(Vh, Wf, bh, bm, C);
    score_h_kernel<<<dim3(1024), dim3(256), 0, stream>>>(C, w2, b2, P0, P1, P2, P3);
    combine_kernel<<<dim3(1024), dim3(256), 0, stream>>>(P0, P1, P2, P3, outp);
  } else if (ws_size >= (size_t)(8u << 20)) {
    _Float16* Vh = (_Float16*)(ws + (4u << 20));         // 2 MB
    _Float16* Wf = (_Float16*)(ws + (6u << 20));         // 2 MB
    cvt_kernel<<<dim3(1024), dim3(256), 0, stream>>>(V, Wh, Wm, Vh, Wf);
    proj_mfma_kernel<<<dim3(1024), dim3(256), 0, stream>>>(Vh, Wf, bh, bm, C);
    score_kernel_r9<<<dim3(512), dim3(256), 0, stream>>>(C, w2, b2, outp);
  } else {
    proj_kernel<<<dim3(256), dim3(256), 0, stream>>>(V, Wh, bh, Wm, bm, C);
    score_kernel_r9<<<dim3(512), dim3(256), 0, stream>>>(C, w2, b2, outp);
  }
}